// Round 1
// 1001.214 us; speedup vs baseline: 1.4523x; 1.4523x over previous
//
#include <hip/hip_runtime.h>
#include <math.h>

#define NG 360
#define NV 100
#define ND 32
#define NU 512
#define NT 15
#define NVOC 5000
#define NH 8
#define NE 544
#define NHD 68
#define OFF_SCORES 4800000
#define INV_SQRT_HD 0.12126781f
#define CS_SCALE 43.65636f

typedef short bf16x8 __attribute__((ext_vector_type(8)));
typedef float f32x4 __attribute__((ext_vector_type(4)));
typedef unsigned short u16x4 __attribute__((ext_vector_type(4)));

__device__ __forceinline__ float leaky(float x) { return x >= 0.f ? x : 0.2f * x; }
__device__ __forceinline__ float sigm(float x) { return 1.f / (1.f + expf(-x)); }
__device__ __forceinline__ unsigned short f2bf(float x) {
    unsigned b = __float_as_uint(x);
    return (unsigned short)((b + 0x7FFFu + ((b >> 16) & 1u)) >> 16);
}
__device__ __forceinline__ float lo16(unsigned p) { return __uint_as_float(p << 16); }
__device__ __forceinline__ float hi16(unsigned p) { return __uint_as_float(p & 0xffff0000u); }

// ---------- Weight prep ----------

// plain bf16 row-major [rows][K] from fp32 (ldw stride, col0 offset)
__global__ __launch_bounds__(256) void kCvt(const float* __restrict__ W, int ldw, int col0,
                                            int K, int total, unsigned short* __restrict__ o) {
    int idx = (int)blockIdx.x * 256 + (int)threadIdx.x;
    if (idx >= total) return;
    int r = idx / K, k = idx - r * K;
    o[idx] = f2bf(W[(size_t)r * ldw + col0 + k]);
}

// W2 -> bf16 [5008][256] (8 pad rows zeroed)
__global__ __launch_bounds__(256) void kCvtW2(const float* __restrict__ W2,
                                              unsigned short* __restrict__ W2bf) {
    int idx = (int)blockIdx.x * 256 + (int)threadIdx.x;
    if (idx < NVOC * 256) W2bf[idx] = f2bf(W2[idx]);
    else if (idx < 5008 * 256) W2bf[idx] = 0;
}

// ---------- Precompute ----------

__global__ void k_transpose_feat(const float* __restrict__ features, float* __restrict__ fX) {
    __shared__ float tile[64 * 65];
    int c0 = (int)blockIdx.x * 64;
    int tl = (int)threadIdx.x;
    int c = tl & 63, q0 = tl >> 6;
    for (int i = 0; i < 16; ++i) {
        int b = q0 + (i << 2);
        int col = c0 + c;
        float v = (col < NG * NV) ? features[b * (NG * NV) + col] : 0.f;
        tile[c * 65 + b] = v;
    }
    __syncthreads();
    int b2 = tl & 63, cr = tl >> 6;
    for (int i = 0; i < 16; ++i) {
        int c2 = cr + (i << 2);
        int col = c0 + c2;
        if (col < NG * NV) fX[col * 64 + b2] = tile[c2 * 65 + b2];
    }
}

// encoder: writes featT [(g*32+d)][b] and featB [b][g][d]
__global__ __launch_bounds__(256) void k_encoder2(
        const float* __restrict__ fX, const float* __restrict__ enc_W,
        const float* __restrict__ enc_b, const float* __restrict__ enc_g,
        const float* __restrict__ enc_beta, float* __restrict__ featT,
        float* __restrict__ featB) {
    __shared__ float fxs[6400];
    __shared__ float ps[256], pq[256];
    int g = (int)blockIdx.x, tid = (int)threadIdx.x;
    #pragma unroll
    for (int k = 0; k < 25; ++k) fxs[tid + k * 256] = fX[g * 6400 + tid + k * 256];
    __syncthreads();
    int lane = tid & 63, w = tid >> 6, d0 = w * 8;
    float acc[8];
    #pragma unroll
    for (int j = 0; j < 8; ++j) acc[j] = enc_b[g * 32 + d0 + j];
    const float* wb = enc_W + g * 3200 + d0 * 100;
    #pragma unroll 4
    for (int v = 0; v < 100; ++v) {
        float fv = fxs[v * 64 + lane];
        #pragma unroll
        for (int j = 0; j < 8; ++j) acc[j] += fv * wb[j * 100 + v];
    }
    float sm = 0.f, sq = 0.f;
    #pragma unroll
    for (int j = 0; j < 8; ++j) { sm += acc[j]; sq += acc[j] * acc[j]; }
    ps[tid] = sm; pq[tid] = sq;
    __syncthreads();
    float m = (ps[lane] + ps[64 + lane] + ps[128 + lane] + ps[192 + lane]) * (1.f / 32.f);
    float q = (pq[lane] + pq[64 + lane] + pq[128 + lane] + pq[192 + lane]);
    float var = q * (1.f / 32.f) - m * m;
    float rstd = 1.f / sqrtf(var + 1e-5f);
    #pragma unroll
    for (int j = 0; j < 8; ++j) {
        int d = d0 + j;
        float x = (acc[j] - m) * rstd * enc_g[d] + enc_beta[d];
        x = leaky(x);
        featT[(g * 32 + d) * 64 + lane] = x;
        featB[((size_t)lane * NG + g) * 32 + d] = x;
    }
}

__global__ void k_init_state(const float* __restrict__ a0, const float* __restrict__ c0,
                             float* __restrict__ aT0, float* __restrict__ cT) {
    __shared__ float tile[64 * 65];
    int which = (int)blockIdx.x >> 3;
    int t0 = ((int)blockIdx.x & 7) * 64;
    const float* src = which ? c0 : a0;
    int tl = (int)threadIdx.x;
    int c = tl & 63, q0 = tl >> 6;
    for (int i = 0; i < 16; ++i) {
        int b = q0 + (i << 2);
        tile[c * 65 + b] = src[b * NU + t0 + c];
    }
    __syncthreads();
    int b2 = tl & 63, cr = tl >> 6;
    for (int i = 0; i < 16; ++i) {
        int c2 = cr + (i << 2);
        float v = tile[c2 * 65 + b2];
        int idx = (t0 + c2) * 64 + b2;
        if (which) cT[idx] = v;
        else aT0[idx] = v;
    }
}

// xbf[(t*64+b)][u] bf16
__global__ void kEmbed(const int* __restrict__ text, const float* __restrict__ emb,
                       unsigned short* __restrict__ xbf) {
    int t = (int)blockIdx.x, tid = (int)threadIdx.x;
    int b = tid >> 2, seg = (tid & 3) * 128;
    int row = text[b * NT + t];
    const float* er = emb + (size_t)row * NU;
    unsigned short* dst = xbf + ((size_t)t * 64 + b) * 512;
    for (int i = 0; i < 128; ++i) dst[seg + i] = f2bf(er[seg + i]);
}

__global__ void k_featmean(const float* __restrict__ featT, float* __restrict__ fmean) {
    int wid = __builtin_amdgcn_readfirstlane((int)blockIdx.x * 4 + ((int)threadIdx.x >> 6));
    int lane = (int)threadIdx.x & 63;
    if (wid >= ND) return;
    float s = 0.f;
    for (int g = 0; g < NG; ++g) s += featT[(g * ND + wid) * 64 + lane];
    fmean[wid * 64 + lane] = s * (1.f / 360.f);
}

__global__ void k_qmean(const float* __restrict__ fmean, const float* __restrict__ in_w,
                        float* __restrict__ qmean) {
    int wid = __builtin_amdgcn_readfirstlane((int)blockIdx.x * 4 + ((int)threadIdx.x >> 6));
    int lane = (int)threadIdx.x & 63;
    if (wid >= 68) return;
    int e0 = wid * 8;
    float acc[8];
    #pragma unroll
    for (int jj = 0; jj < 8; ++jj) acc[jj] = 0.f;
    #pragma unroll 4
    for (int d = 0; d < ND; ++d) {
        float fv = fmean[d * 64 + lane];
        #pragma unroll
        for (int jj = 0; jj < 8; ++jj) acc[jj] += fv * in_w[(e0 + jj) * NE + d];
    }
    #pragma unroll
    for (int jj = 0; jj < 8; ++jj) qmean[(e0 + jj) * 64 + lane] = acc[jj];
}

// m[b][h*32+d'] = sum_{d<68} Wk[h*68+d][d'] * qa[(h*68+d)][b]   (8 blocks, 32 waves)
__global__ __launch_bounds__(256) void kM(const float* __restrict__ qa,
                                          const float* __restrict__ in_w,
                                          float* __restrict__ m) {
    int wid = __builtin_amdgcn_readfirstlane((int)blockIdx.x * 4 + ((int)threadIdx.x >> 6));
    int lane = (int)threadIdx.x & 63;
    int h = wid >> 2, dg = (wid & 3) * 8;
    float acc[8] = {0.f, 0.f, 0.f, 0.f, 0.f, 0.f, 0.f, 0.f};
    for (int d = 0; d < NHD; ++d) {
        float qv = qa[(h * NHD + d) * 64 + lane];
        const float* wr = in_w + (size_t)(NE + h * NHD + d) * NE + dg;
        #pragma unroll
        for (int i = 0; i < 8; ++i) acc[i] = fmaf(qv, wr[i], acc[i]);
    }
    #pragma unroll
    for (int i = 0; i < 8; ++i) m[(size_t)lane * 256 + h * 32 + dg + i] = acc[i];
}

// cSb[b][h][j] = CS_SCALE * feat[b,j]·mq[b,h]   (96 blocks, lane = j)
__global__ __launch_bounds__(256) void kCS(const float* __restrict__ mq,
                                           const float* __restrict__ featB,
                                           float* __restrict__ cSb) {
    int wid = __builtin_amdgcn_readfirstlane((int)blockIdx.x * 4 + ((int)threadIdx.x >> 6));
    int lane = (int)threadIdx.x & 63;
    int b = wid / 6, jt = wid % 6;
    int j = jt * 64 + lane;
    bool valid = j < NG;
    int jc = valid ? j : 0;
    const float* mb = mq + (size_t)b * 256;
    const float* fb = featB + ((size_t)b * NG + jc) * 32;
    float v[8] = {0.f, 0.f, 0.f, 0.f, 0.f, 0.f, 0.f, 0.f};
    #pragma unroll
    for (int dc = 0; dc < 32; dc += 4) {
        float4 f = *(const float4*)(fb + dc);
        #pragma unroll
        for (int h = 0; h < 8; ++h) {
            v[h] = fmaf(f.x, mb[h * 32 + dc], v[h]);
            v[h] = fmaf(f.y, mb[h * 32 + dc + 1], v[h]);
            v[h] = fmaf(f.z, mb[h * 32 + dc + 2], v[h]);
            v[h] = fmaf(f.w, mb[h * 32 + dc + 3], v[h]);
        }
    }
    if (valid) {
        #pragma unroll
        for (int h = 0; h < 8; ++h)
            cSb[(size_t)b * 2880 + h * NG + j] = v[h] * CS_SCALE;
    }
}

// gihxAll[t][n][b] via MFMA: M=2048 (Wih rows), cols = t*64+b, K=512. 1920 blocks.
__global__ __launch_bounds__(256) void kGihxMF(const unsigned short* __restrict__ Wihx,
                                               const unsigned short* __restrict__ xbf,
                                               float* __restrict__ gihxAll) {
    int wid = __builtin_amdgcn_readfirstlane((int)blockIdx.x * 4 + ((int)threadIdx.x >> 6));
    int lane = (int)threadIdx.x & 63;
    int mt = wid / 60, nt = wid % 60;
    int m0 = mt * 16, col = lane & 15, q = lane >> 4;
    const unsigned short* aB = Wihx + (size_t)(m0 + col) * 512 + q * 8;
    const unsigned short* bB = xbf + (size_t)(nt * 16 + col) * 512 + q * 8;
    f32x4 acc = {0.f, 0.f, 0.f, 0.f};
    #pragma unroll
    for (int kk = 0; kk < 16; ++kk) {
        bf16x8 af = *(const bf16x8*)(aB + kk * 32);
        bf16x8 bf = *(const bf16x8*)(bB + kk * 32);
        acc = __builtin_amdgcn_mfma_f32_16x16x32_bf16(af, bf, acc, 0, 0, 0);
    }
    int gcol = nt * 16 + col, t = gcol >> 6, b = gcol & 63;
    float* dst = gihxAll + (size_t)t * (4 * NU * 64);
    #pragma unroll
    for (int r = 0; r < 4; ++r) {
        int row = m0 + q * 4 + r;
        dst[row * 64 + b] = acc[r];
    }
}

// ---------- Per-step ----------

// LN(h_{t-1}) -> bf16 abf[b][512] (MFMA B-operand layout), and leaky version into
// sbfAll[(t-1)*64+b][512] for the post-loop head. t==0: abf from aT0 directly.
// 8 blocks, each handles 64 u-rows; LDS transpose for coalesced 2B writes.
__global__ __launch_bounds__(256) void kLN(
        const float* __restrict__ aT0, const float* __restrict__ hTall,
        const float* __restrict__ lnPS, const float* __restrict__ lnPQ,
        const float* __restrict__ ln_g, const float* __restrict__ ln_b,
        unsigned short* __restrict__ abf, unsigned short* __restrict__ sbf, int t) {
    __shared__ float tile[64 * 65];
    int tid = (int)threadIdx.x;
    int b = tid & 63, r = tid >> 6;
    int u0 = (int)blockIdx.x * 64;
    if (t > 0) {
        const float* pS = lnPS + (size_t)(t - 1) * 2048;
        const float* pQ = lnPQ + (size_t)(t - 1) * 2048;
        float ms = 0.f, qs = 0.f;
        #pragma unroll 8
        for (int i = 0; i < 32; ++i) { ms += pS[i * 64 + b]; qs += pQ[i * 64 + b]; }
        float m = ms * (1.f / 512.f);
        float var = qs * (1.f / 512.f) - m * m;
        float rstd = 1.f / sqrtf(var + 1e-5f);
        float mneg = -m * rstd;
        const float* src = hTall + (size_t)(t - 1) * (NU * 64);
        #pragma unroll
        for (int i = 0; i < 16; ++i) {
            int ul = r + i * 4;
            int u = u0 + ul;
            float x = src[u * 64 + b];
            tile[b * 65 + ul] = fmaf(fmaf(x, rstd, mneg), ln_g[u], ln_b[u]);
        }
    } else {
        #pragma unroll
        for (int i = 0; i < 16; ++i) {
            int ul = r + i * 4;
            tile[b * 65 + ul] = aT0[(u0 + ul) * 64 + b];
        }
    }
    __syncthreads();
    bool doS = t > 0;
    unsigned short* srow = sbf + (size_t)(t - 1) * 64 * NU;
    #pragma unroll
    for (int i = 0; i < 16; ++i) {
        int idx = tid + i * 256;
        int bb = idx >> 6, ul = idx & 63;
        float v = tile[bb * 65 + ul];
        abf[(size_t)bb * NU + u0 + ul] = f2bf(v);
        if (doS) srow[(size_t)bb * NU + u0 + ul] = f2bf(leaky(v));
    }
}

// MFMA: [qa(544); ghh(2048)] = WA[2592][512] · abf[64][512]^T. 162 blocks.
__global__ __launch_bounds__(256) void kAMF(
        const unsigned short* __restrict__ WA, const unsigned short* __restrict__ abf,
        const float* __restrict__ in_b,
        float* __restrict__ qaT, float* __restrict__ ghh) {
    int wid = __builtin_amdgcn_readfirstlane((int)blockIdx.x * 4 + ((int)threadIdx.x >> 6));
    int lane = (int)threadIdx.x & 63;
    int mt = wid >> 2, bt = wid & 3;
    int m0 = mt * 16, col = lane & 15, q = lane >> 4;
    const unsigned short* aB = WA + (size_t)(m0 + col) * NU + q * 8;
    const unsigned short* bB = abf + (size_t)(bt * 16 + col) * NU + q * 8;
    f32x4 acc = {0.f, 0.f, 0.f, 0.f};
    #pragma unroll
    for (int kk = 0; kk < 16; ++kk) {
        bf16x8 af = *(const bf16x8*)(aB + kk * 32);
        bf16x8 bf = *(const bf16x8*)(bB + kk * 32);
        acc = __builtin_amdgcn_mfma_f32_16x16x32_bf16(af, bf, acc, 0, 0, 0);
    }
    int b = bt * 16 + col;
    if (m0 < 544) {  // wave-uniform: 544 = 34 full tiles
        #pragma unroll
        for (int r = 0; r < 4; ++r) {
            int row = m0 + q * 4 + r;
            qaT[row * 64 + b] = acc[r] + in_b[row];
        }
    } else {
        #pragma unroll
        for (int r = 0; r < 4; ++r) {
            int row = m0 - 544 + q * 4 + r;
            ghh[row * 64 + b] = acc[r];
        }
    }
}

// 96 blocks, lane = j: e=exp(feat·m/√68), partials; evb[b][h][j]
__global__ __launch_bounds__(256) void kB(
        const float* __restrict__ m, const float* __restrict__ featB,
        const float* __restrict__ cSb,
        float* __restrict__ evb, float* __restrict__ sevP, float* __restrict__ cevP) {
    int wid = __builtin_amdgcn_readfirstlane((int)blockIdx.x * 4 + ((int)threadIdx.x >> 6));
    int lane = (int)threadIdx.x & 63;
    int b = wid / 6, jt = wid % 6;
    int j = jt * 64 + lane;
    bool valid = j < NG;
    int jc = valid ? j : 0;
    const float* mb = m + (size_t)b * 256;
    const float* fb = featB + ((size_t)b * NG + jc) * 32;
    float v[8] = {0.f, 0.f, 0.f, 0.f, 0.f, 0.f, 0.f, 0.f};
    #pragma unroll
    for (int dc = 0; dc < 32; dc += 4) {
        float4 f = *(const float4*)(fb + dc);
        #pragma unroll
        for (int h = 0; h < 8; ++h) {
            v[h] = fmaf(f.x, mb[h * 32 + dc], v[h]);
            v[h] = fmaf(f.y, mb[h * 32 + dc + 1], v[h]);
            v[h] = fmaf(f.z, mb[h * 32 + dc + 2], v[h]);
            v[h] = fmaf(f.w, mb[h * 32 + dc + 3], v[h]);
        }
    }
    float eS[8], eC[8];
    #pragma unroll
    for (int h = 0; h < 8; ++h) {
        float e = valid ? expf(v[h] * INV_SQRT_HD) : 0.f;
        float c = valid ? cSb[(size_t)b * 2880 + h * NG + j] : 0.f;
        if (valid) evb[(size_t)b * 2880 + h * NG + j] = e;
        eS[h] = e; eC[h] = c * e;
    }
    #pragma unroll
    for (int h = 0; h < 8; ++h) {
        #pragma unroll
        for (int off = 32; off > 0; off >>= 1) {
            eS[h] += __shfl_xor(eS[h], off);
            eC[h] += __shfl_xor(eC[h], off);
        }
    }
    if (lane == 0) {
        #pragma unroll
        for (int h = 0; h < 8; ++h) {
            sevP[b * 48 + jt * 8 + h] = eS[h];
            cevP[b * 48 + jt * 8 + h] = eC[h];
        }
    }
}

// 64 blocks (one per b): combine partials, W -> out scores + complete ctx[d][b].
__global__ __launch_bounds__(256) void kC(
        const float* __restrict__ evb, const float* __restrict__ cSb,
        const float* __restrict__ sevP, const float* __restrict__ cevP,
        const float* __restrict__ featB,
        float* __restrict__ out, float* __restrict__ ctx, int t) {
    __shared__ float SevL[8], CevL[8], WL[360], sbuf[48], cbuf[48], cpart[256];
    int b = (int)blockIdx.x, tid = (int)threadIdx.x;
    if (tid < 48) { sbuf[tid] = sevP[b * 48 + tid]; cbuf[tid] = cevP[b * 48 + tid]; }
    __syncthreads();
    if (tid < 8) {
        float s = 0.f, c = 0.f;
        #pragma unroll
        for (int jt = 0; jt < 6; ++jt) { s += sbuf[jt * 8 + tid]; c += cbuf[jt * 8 + tid]; }
        SevL[tid] = s; CevL[tid] = c;
    }
    __syncthreads();
    float invS[8], cevM[8];
    #pragma unroll
    for (int h = 0; h < 8; ++h) {
        float iv = 1.f / SevL[h];
        invS[h] = iv;
        cevM[h] = CevL[h] * iv;
    }
    for (int j = tid; j < NG; j += 256) {
        float acc = 0.f;
        #pragma unroll
        for (int h = 0; h < 8; ++h) {
            float e = evb[(size_t)b * 2880 + h * NG + j];
            float c = cSb[(size_t)b * 2880 + h * NG + j];
            acc += e * invS[h] * (1.f + (c - cevM[h]) * (1.f / 360.f));
        }
        float W = acc * 0.125f;
        WL[j] = W;
        out[OFF_SCORES + (size_t)b * (NT * NG) + t * NG + j] = W;
    }
    __syncthreads();
    int d = tid & 31, sl = tid >> 5;
    float a = 0.f;
    for (int i = 0; i < 45; ++i) {
        int j = sl * 45 + i;
        a += WL[j] * featB[((size_t)b * NG + j) * 32 + d];
    }
    cpart[tid] = a;
    __syncthreads();
    if (tid < 32) {
        float s = 0.f;
        #pragma unroll
        for (int ss = 0; ss < 8; ++ss) s += cpart[ss * 32 + tid];
        ctx[tid * 64 + b] = s;
    }
}

// 32 blocks (16 u each): gates + cell + h + LN partials. ctx read directly.
__global__ __launch_bounds__(256) void kF1(
        const float* __restrict__ gihxT, const float* __restrict__ ghh,
        const float* __restrict__ ctx, const float* __restrict__ Wih,
        const float* __restrict__ bih, const float* __restrict__ bhh,
        float* __restrict__ cT, float* __restrict__ hDst,
        float* __restrict__ lnPS, float* __restrict__ lnPQ) {
    __shared__ float rS[256], rQ[256];
    int tid = (int)threadIdx.x, bid = (int)blockIdx.x;
    int lane = tid & 63, w = tid >> 6;
    float cx[32];
    #pragma unroll 8
    for (int d = 0; d < 32; ++d) cx[d] = ctx[d * 64 + lane];
    int u0 = bid * 16 + w * 4;
    float ssum = 0.f, qsum = 0.f;
    for (int i = 0; i < 4; ++i) {
        int u = u0 + i;
        float g4[4];
        #pragma unroll
        for (int q = 0; q < 4; ++q) {
            int n = q * NU + u;
            float gv = gihxT[n * 64 + lane] + ghh[n * 64 + lane] + bih[n] + bhh[n];
            const float* wr = Wih + (size_t)n * NE;
            #pragma unroll
            for (int d = 0; d < 32; ++d) gv += cx[d] * wr[d];
            g4[q] = gv;
        }
        float ig = sigm(g4[0]), fg = sigm(g4[1]), gg = tanhf(g4[2]), og = sigm(g4[3]);
        float cn = fg * cT[u * 64 + lane] + ig * gg;
        cT[u * 64 + lane] = cn;
        float hv = og * tanhf(cn);
        hDst[u * 64 + lane] = hv;
        ssum += hv; qsum += hv * hv;
    }
    rS[tid] = ssum; rQ[tid] = qsum;
    __syncthreads();
    if (tid < 64) {
        lnPS[bid * 64 + tid] = rS[tid] + rS[64 + tid] + rS[128 + tid] + rS[192 + tid];
        lnPQ[bid * 64 + tid] = rQ[tid] + rQ[64 + tid] + rQ[128 + tid] + rQ[192 + tid];
    }
}

// ---------- Post-loop head ----------

// MFMA: h1[256][960] = leaky(W1x[256][512] · sbf[960][512]^T + b1); bf16 packed
// directly into kLogitsMF's B layout h1bf[t*64+b][256]. 240 blocks.
__global__ __launch_bounds__(256) void kHeadMF(
        const unsigned short* __restrict__ W1x, const unsigned short* __restrict__ sbf,
        const float* __restrict__ b1, unsigned short* __restrict__ h1bf) {
    int wid = __builtin_amdgcn_readfirstlane((int)blockIdx.x * 4 + ((int)threadIdx.x >> 6));
    int lane = (int)threadIdx.x & 63;
    int mt = wid / 60, nt = wid % 60;
    int m0 = mt * 16, col = lane & 15, q = lane >> 4;
    const unsigned short* aB = W1x + (size_t)(m0 + col) * NU + q * 8;
    const unsigned short* bB = sbf + (size_t)(nt * 16 + col) * NU + q * 8;
    f32x4 acc = {0.f, 0.f, 0.f, 0.f};
    #pragma unroll
    for (int kk = 0; kk < 16; ++kk) {
        bf16x8 af = *(const bf16x8*)(aB + kk * 32);
        bf16x8 bf = *(const bf16x8*)(bB + kk * 32);
        acc = __builtin_amdgcn_mfma_f32_16x16x32_bf16(af, bf, acc, 0, 0, 0);
    }
    int gcol = nt * 16 + col;
    u16x4 pk;
    #pragma unroll
    for (int r = 0; r < 4; ++r) {
        float v = leaky(acc[r] + b1[m0 + q * 4 + r]);
        pk[r] = f2bf(v);
    }
    *(u16x4*)(h1bf + (size_t)gcol * 256 + m0 + q * 4) = pk;
}

// MFMA logits: 4695 blocks
__global__ __launch_bounds__(256) void kLogitsMF(const unsigned short* __restrict__ W2bf,
                                                 const unsigned short* __restrict__ h1bfT,
                                                 const float* __restrict__ b2,
                                                 float* __restrict__ lgAll, float* __restrict__ zPm) {
    int wid = __builtin_amdgcn_readfirstlane((int)blockIdx.x * 4 + ((int)threadIdx.x >> 6));
    int lane = (int)threadIdx.x & 63;
    int t = wid / 1252;
    int rem = wid - t * 1252;
    int mt = rem >> 2, ntile = rem & 3;
    int m0 = mt * 16, b0 = ntile * 16;
    int q = lane >> 4, col = lane & 15;
    const unsigned short* aBase = W2bf + (size_t)(m0 + col) * 256 + q * 8;
    const unsigned short* bBase = h1bfT + ((size_t)t * 64 + b0 + col) * 256 + q * 8;
    f32x4 acc = {0.f, 0.f, 0.f, 0.f};
    #pragma unroll
    for (int kk = 0; kk < 8; ++kk) {
        bf16x8 af = *(const bf16x8*)(aBase + kk * 32);
        bf16x8 bf = *(const bf16x8*)(bBase + kk * 32);
        acc = __builtin_amdgcn_mfma_f32_16x16x32_bf16(af, bf, acc, 0, 0, 0);
    }
    float eS = 0.f;
    #pragma unroll
    for (int r = 0; r < 4; ++r) {
        int row = m0 + q * 4 + r;
        if (row < NVOC) {
            float lg = acc[r] + b2[row];
            lgAll[((size_t)t * NVOC + row) * 64 + b0 + col] = lg;
            eS += expf(lg);
        }
    }
    eS += __shfl_xor(eS, 16);
    eS += __shfl_xor(eS, 32);
    if (lane < 16)
        zPm[((size_t)t * 313 + mt) * 64 + b0 + col] = eS;
}

__global__ __launch_bounds__(256) void kZc(const float* __restrict__ zPm, float* __restrict__ zQ) {
    __shared__ float red[256];
    int bid = (int)blockIdx.x, tid = (int)threadIdx.x;
    int t = bid >> 2, qd = bid & 3;
    int lane = tid & 63, w = tid >> 6;
    float p = 0.f;
    for (int ii = w; ii < 79; ii += 4) {
        int i = qd * 79 + ii;
        if (i < 313) p += zPm[((size_t)t * 313 + i) * 64 + lane];
    }
    red[tid] = p;
    __syncthreads();
    if (tid < 64) zQ[bid * 64 + tid] = red[tid] + red[64 + tid] + red[128 + tid] + red[192 + tid];
}

__global__ __launch_bounds__(256) void kOut(const float* __restrict__ lgAll,
                                            const float* __restrict__ zQ, float* __restrict__ out) {
    __shared__ float tile[64 * 65];
    int bid = (int)blockIdx.x;
    int t = bid / 79, nt = bid % 79;
    int n0 = nt * 64;
    int tid = (int)threadIdx.x, lane = tid & 63, w = tid >> 6;
    const float* lg = lgAll + (size_t)t * (NVOC * 64);
    float z = zQ[(t * 4) * 64 + lane] + zQ[(t * 4 + 1) * 64 + lane] +
              zQ[(t * 4 + 2) * 64 + lane] + zQ[(t * 4 + 3) * 64 + lane];
    float invZ = 1.f / z;
    for (int i = 0; i < 16; ++i) {
        int r = w * 16 + i, n = n0 + r;
        if (n < NVOC) tile[r * 65 + lane] = expf(lg[n * 64 + lane]) * invZ;
    }
    __syncthreads();
    for (int i = 0; i < 16; ++i) {
        int b = w * 16 + i;
        int n = n0 + lane;
        if (n < NVOC) out[(size_t)b * (NT * NVOC) + t * NVOC + n] = tile[lane * 65 + b];
    }
}

// ---------- Launch ----------
extern "C" void kernel_launch(void* const* d_in, const int* in_sizes, int n_in,
                              void* d_out, int out_size, void* d_ws, size_t ws_size,
                              hipStream_t stream) {
    const float* features = (const float*)d_in[0];
    const int*   text     = (const int*)d_in[1];
    const float* a0       = (const float*)d_in[2];
    const float* c0       = (const float*)d_in[3];
    const float* enc_W    = (const float*)d_in[4];
    const float* enc_b    = (const float*)d_in[5];
    const float* enc_g    = (const float*)d_in[6];
    const float* enc_beta = (const float*)d_in[7];
    const float* emb      = (const float*)d_in[8];
    const float* in_w     = (const float*)d_in[9];
    const float* in_b     = (const float*)d_in[10];
    const float* Wih      = (const float*)d_in[11];
    const float* Whh      = (const float*)d_in[12];
    const float* bih      = (const float*)d_in[13];
    const float* bhh      = (const float*)d_in[14];
    const float* ln_g     = (const float*)d_in[15];
    const float* ln_b     = (const float*)d_in[16];
    const float* W1       = (const float*)d_in[17];
    const float* b1       = (const float*)d_in[18];
    const float* W2       = (const float*)d_in[19];
    const float* b2       = (const float*)d_in[20];
    float* out = (float*)d_out;

    float* ws = (float*)d_ws;
    size_t off = 0;
    auto alloc = [&](size_t n) { float* p = ws + off; off += (n + 63) & ~(size_t)63; return p; };
    float* lgAll   = alloc((size_t)NT * NVOC * 64);   // aliased as fX pre-loop
    float* fX      = lgAll;
    float* featT   = alloc((size_t)NG * ND * 64);
    float* featB   = alloc((size_t)64 * NG * ND);
    float* gihxAll = alloc((size_t)NT * 4 * NU * 64);
    float* fmean   = alloc((size_t)ND * 64);
    float* qmean   = alloc((size_t)NE * 64);
    float* mq      = alloc((size_t)64 * 256);
    float* mstep   = alloc((size_t)64 * 256);
    float* cSb     = alloc((size_t)64 * NH * NG);
    float* evb     = alloc((size_t)64 * NH * NG);
    float* sevP    = alloc((size_t)64 * 48);
    float* cevP    = alloc((size_t)64 * 48);
    float* aT0     = alloc((size_t)NU * 64);
    float* cT_     = alloc((size_t)NU * 64);
    float* hTall   = alloc((size_t)NT * NU * 64);
    float* qaT     = alloc((size_t)NE * 64);
    float* ghh     = alloc((size_t)4 * NU * 64);
    float* ctx     = alloc((size_t)ND * 64);
    float* lnPS    = alloc((size_t)NT * 32 * 64);
    float* lnPQ    = alloc((size_t)NT * 32 * 64);
    float* zPm     = alloc((size_t)NT * 313 * 64);
    float* zQ      = alloc((size_t)NT * 4 * 64);
    unsigned short* WA   = (unsigned short*)alloc((size_t)2592 * 256);  // [2592][512] bf16: Wq rows 0..543, Whh rows 544..2591
    unsigned short* W1x  = (unsigned short*)alloc((size_t)256 * 256);   // [256][512] bf16
    unsigned short* abf  = (unsigned short*)alloc((size_t)64 * 256);    // [64][512] bf16, per-step a=LN(h)
    unsigned short* sbf  = (unsigned short*)alloc((size_t)960 * 256);   // [960][512] bf16, leaky(LN(h_t)) all t
    unsigned short* Wihx = (unsigned short*)alloc((size_t)2048 * 256);
    unsigned short* xbf  = (unsigned short*)alloc((size_t)960 * 256);
    unsigned short* W2bf = (unsigned short*)alloc((size_t)5008 * 128);
    unsigned short* h1bf = (unsigned short*)alloc((size_t)NT * 64 * 128);  // [960][256] bf16

    // weight prep
    kCvt<<<1088, 256, 0, stream>>>(in_w, NE, ND, 512, 544 * 512, WA);
    kCvt<<<4096, 256, 0, stream>>>(Whh, NU, 0, 512, 2048 * 512, WA + (size_t)544 * 512);
    kCvt<<<512, 256, 0, stream>>>(W1, NU, 0, 512, 256 * 512, W1x);
    kCvt<<<4096, 256, 0, stream>>>(Wih, NE, ND, 512, 2048 * 512, Wihx);
    kCvtW2<<<5008, 256, 0, stream>>>(W2, W2bf);

    // precompute
    k_transpose_feat<<<563, 256, 0, stream>>>(features, fX);
    k_encoder2<<<NG, 256, 0, stream>>>(fX, enc_W, enc_b, enc_g, enc_beta, featT, featB);
    k_init_state<<<16, 256, 0, stream>>>(a0, c0, aT0, cT_);
    kEmbed<<<NT, 256, 0, stream>>>(text, emb, xbf);
    k_featmean<<<8, 256, 0, stream>>>(featT, fmean);
    k_qmean<<<17, 256, 0, stream>>>(fmean, in_w, qmean);
    kM<<<8, 256, 0, stream>>>(qmean, in_w, mq);
    kCS<<<96, 256, 0, stream>>>(mq, featB, cSb);
    kGihxMF<<<1920, 256, 0, stream>>>(Wihx, xbf, gihxAll);

    for (int t = 0; t < NT; ++t) {
        kLN<<<8, 256, 0, stream>>>(aT0, hTall, lnPS, lnPQ, ln_g, ln_b, abf, sbf, t);
        kAMF<<<162, 256, 0, stream>>>(WA, abf, in_b, qaT, ghh);
        kM<<<8, 256, 0, stream>>>(qaT, in_w, mstep);
        kB<<<96, 256, 0, stream>>>(mstep, featB, cSb, evb, sevP, cevP);
        kC<<<64, 256, 0, stream>>>(evb, cSb, sevP, cevP, featB, out, ctx, t);
        kF1<<<32, 256, 0, stream>>>(gihxAll + (size_t)t * 4 * NU * 64, ghh, ctx, Wih,
                                    bih, bhh, cT_, hTall + (size_t)t * NU * 64,
                                    lnPS + (size_t)t * 2048, lnPQ + (size_t)t * 2048);
    }

    // final LN (h_14 -> sbf rows 14*64..) then MFMA head
    kLN<<<8, 256, 0, stream>>>(aT0, hTall, lnPS, lnPQ, ln_g, ln_b, abf, sbf, NT);
    kHeadMF<<<240, 256, 0, stream>>>(W1x, sbf, b1, h1bf);
    kLogitsMF<<<4695, 256, 0, stream>>>(W2bf, h1bf, b2, lgAll, zPm);
    kZc<<<60, 256, 0, stream>>>(zPm, zQ);
    kOut<<<NT * 79, 256, 0, stream>>>(lgAll, zQ, out);
}

// Round 2
// 947.951 us; speedup vs baseline: 1.5339x; 1.0562x over previous
//
#include <hip/hip_runtime.h>
#include <math.h>

#define NG 360
#define NV 100
#define ND 32
#define NU 512
#define NT 15
#define NVOC 5000
#define NH 8
#define NE 544
#define NHD 68
#define OFF_SCORES 4800000
#define INV_SQRT_HD 0.12126781f
#define CS_SCALE 43.65636f

typedef short bf16x8 __attribute__((ext_vector_type(8)));
typedef float f32x4 __attribute__((ext_vector_type(4)));
typedef unsigned short u16x4 __attribute__((ext_vector_type(4)));

__device__ __forceinline__ float leaky(float x) { return x >= 0.f ? x : 0.2f * x; }
__device__ __forceinline__ float sigm(float x) { return 1.f / (1.f + expf(-x)); }
__device__ __forceinline__ unsigned short f2bf(float x) {
    unsigned b = __float_as_uint(x);
    return (unsigned short)((b + 0x7FFFu + ((b >> 16) & 1u)) >> 16);
}

// ---------- Weight prep ----------

// plain bf16 row-major [rows][K] from fp32 (ldw stride, col0 offset)
__global__ __launch_bounds__(256) void kCvt(const float* __restrict__ W, int ldw, int col0,
                                            int K, int total, unsigned short* __restrict__ o) {
    int idx = (int)blockIdx.x * 256 + (int)threadIdx.x;
    if (idx >= total) return;
    int r = idx / K, k = idx - r * K;
    o[idx] = f2bf(W[(size_t)r * ldw + col0 + k]);
}

// W2 -> bf16 [5008][256] (8 pad rows zeroed)
__global__ __launch_bounds__(256) void kCvtW2(const float* __restrict__ W2,
                                              unsigned short* __restrict__ W2bf) {
    int idx = (int)blockIdx.x * 256 + (int)threadIdx.x;
    if (idx < NVOC * 256) W2bf[idx] = f2bf(W2[idx]);
    else if (idx < 5008 * 256) W2bf[idx] = 0;
}

// ---------- Precompute ----------

__global__ void k_transpose_feat(const float* __restrict__ features, float* __restrict__ fX) {
    __shared__ float tile[64 * 65];
    int c0 = (int)blockIdx.x * 64;
    int tl = (int)threadIdx.x;
    int c = tl & 63, q0 = tl >> 6;
    for (int i = 0; i < 16; ++i) {
        int b = q0 + (i << 2);
        int col = c0 + c;
        float v = (col < NG * NV) ? features[b * (NG * NV) + col] : 0.f;
        tile[c * 65 + b] = v;
    }
    __syncthreads();
    int b2 = tl & 63, cr = tl >> 6;
    for (int i = 0; i < 16; ++i) {
        int c2 = cr + (i << 2);
        int col = c0 + c2;
        if (col < NG * NV) fX[col * 64 + b2] = tile[c2 * 65 + b2];
    }
}

// encoder: writes featT [(g*32+d)][b] and featB [b][g][d]
__global__ __launch_bounds__(256) void k_encoder2(
        const float* __restrict__ fX, const float* __restrict__ enc_W,
        const float* __restrict__ enc_b, const float* __restrict__ enc_g,
        const float* __restrict__ enc_beta, float* __restrict__ featT,
        float* __restrict__ featB) {
    __shared__ float fxs[6400];
    __shared__ float ps[256], pq[256];
    int g = (int)blockIdx.x, tid = (int)threadIdx.x;
    #pragma unroll
    for (int k = 0; k < 25; ++k) fxs[tid + k * 256] = fX[g * 6400 + tid + k * 256];
    __syncthreads();
    int lane = tid & 63, w = tid >> 6, d0 = w * 8;
    float acc[8];
    #pragma unroll
    for (int j = 0; j < 8; ++j) acc[j] = enc_b[g * 32 + d0 + j];
    const float* wb = enc_W + g * 3200 + d0 * 100;
    #pragma unroll 4
    for (int v = 0; v < 100; ++v) {
        float fv = fxs[v * 64 + lane];
        #pragma unroll
        for (int j = 0; j < 8; ++j) acc[j] += fv * wb[j * 100 + v];
    }
    float sm = 0.f, sq = 0.f;
    #pragma unroll
    for (int j = 0; j < 8; ++j) { sm += acc[j]; sq += acc[j] * acc[j]; }
    ps[tid] = sm; pq[tid] = sq;
    __syncthreads();
    float m = (ps[lane] + ps[64 + lane] + ps[128 + lane] + ps[192 + lane]) * (1.f / 32.f);
    float q = (pq[lane] + pq[64 + lane] + pq[128 + lane] + pq[192 + lane]);
    float var = q * (1.f / 32.f) - m * m;
    float rstd = 1.f / sqrtf(var + 1e-5f);
    #pragma unroll
    for (int j = 0; j < 8; ++j) {
        int d = d0 + j;
        float x = (acc[j] - m) * rstd * enc_g[d] + enc_beta[d];
        x = leaky(x);
        featT[(g * 32 + d) * 64 + lane] = x;
        featB[((size_t)lane * NG + g) * 32 + d] = x;
    }
}

__global__ void k_init_state(const float* __restrict__ a0, const float* __restrict__ c0,
                             float* __restrict__ aT0, float* __restrict__ cT) {
    __shared__ float tile[64 * 65];
    int which = (int)blockIdx.x >> 3;
    int t0 = ((int)blockIdx.x & 7) * 64;
    const float* src = which ? c0 : a0;
    int tl = (int)threadIdx.x;
    int c = tl & 63, q0 = tl >> 6;
    for (int i = 0; i < 16; ++i) {
        int b = q0 + (i << 2);
        tile[c * 65 + b] = src[b * NU + t0 + c];
    }
    __syncthreads();
    int b2 = tl & 63, cr = tl >> 6;
    for (int i = 0; i < 16; ++i) {
        int c2 = cr + (i << 2);
        float v = tile[c2 * 65 + b2];
        int idx = (t0 + c2) * 64 + b2;
        if (which) cT[idx] = v;
        else aT0[idx] = v;
    }
}

// xbf[(t*64+b)][u] bf16
__global__ void kEmbed(const int* __restrict__ text, const float* __restrict__ emb,
                       unsigned short* __restrict__ xbf) {
    int t = (int)blockIdx.x, tid = (int)threadIdx.x;
    int b = tid >> 2, seg = (tid & 3) * 128;
    int row = text[b * NT + t];
    const float* er = emb + (size_t)row * NU;
    unsigned short* dst = xbf + ((size_t)t * 64 + b) * 512;
    for (int i = 0; i < 128; ++i) dst[seg + i] = f2bf(er[seg + i]);
}

__global__ void k_featmean(const float* __restrict__ featT, float* __restrict__ fmean) {
    int wid = __builtin_amdgcn_readfirstlane((int)blockIdx.x * 4 + ((int)threadIdx.x >> 6));
    int lane = (int)threadIdx.x & 63;
    if (wid >= ND) return;
    float s = 0.f;
    for (int g = 0; g < NG; ++g) s += featT[(g * ND + wid) * 64 + lane];
    fmean[wid * 64 + lane] = s * (1.f / 360.f);
}

__global__ void k_qmean(const float* __restrict__ fmean, const float* __restrict__ in_w,
                        float* __restrict__ qmean) {
    int wid = __builtin_amdgcn_readfirstlane((int)blockIdx.x * 4 + ((int)threadIdx.x >> 6));
    int lane = (int)threadIdx.x & 63;
    if (wid >= 68) return;
    int e0 = wid * 8;
    float acc[8];
    #pragma unroll
    for (int jj = 0; jj < 8; ++jj) acc[jj] = 0.f;
    #pragma unroll 4
    for (int d = 0; d < ND; ++d) {
        float fv = fmean[d * 64 + lane];
        #pragma unroll
        for (int jj = 0; jj < 8; ++jj) acc[jj] += fv * in_w[(e0 + jj) * NE + d];
    }
    #pragma unroll
    for (int jj = 0; jj < 8; ++jj) qmean[(e0 + jj) * 64 + lane] = acc[jj];
}

// m[b][h*32+d'] = sum_{d<68} Wk[h*68+d][d'] * qa[(h*68+d)][b]   (pre-loop only)
__global__ __launch_bounds__(256) void kM(const float* __restrict__ qa,
                                          const float* __restrict__ in_w,
                                          float* __restrict__ m) {
    int wid = __builtin_amdgcn_readfirstlane((int)blockIdx.x * 4 + ((int)threadIdx.x >> 6));
    int lane = (int)threadIdx.x & 63;
    int h = wid >> 2, dg = (wid & 3) * 8;
    float acc[8] = {0.f, 0.f, 0.f, 0.f, 0.f, 0.f, 0.f, 0.f};
    for (int d = 0; d < NHD; ++d) {
        float qv = qa[(h * NHD + d) * 64 + lane];
        const float* wr = in_w + (size_t)(NE + h * NHD + d) * NE + dg;
        #pragma unroll
        for (int i = 0; i < 8; ++i) acc[i] = fmaf(qv, wr[i], acc[i]);
    }
    #pragma unroll
    for (int i = 0; i < 8; ++i) m[(size_t)lane * 256 + h * 32 + dg + i] = acc[i];
}

// cSb[b][h][j] = CS_SCALE * feat[b,j]·mq[b,h]   (96 blocks, lane = j)
__global__ __launch_bounds__(256) void kCS(const float* __restrict__ mq,
                                           const float* __restrict__ featB,
                                           float* __restrict__ cSb) {
    int wid = __builtin_amdgcn_readfirstlane((int)blockIdx.x * 4 + ((int)threadIdx.x >> 6));
    int lane = (int)threadIdx.x & 63;
    int b = wid / 6, jt = wid % 6;
    int j = jt * 64 + lane;
    bool valid = j < NG;
    int jc = valid ? j : 0;
    const float* mb = mq + (size_t)b * 256;
    const float* fb = featB + ((size_t)b * NG + jc) * 32;
    float v[8] = {0.f, 0.f, 0.f, 0.f, 0.f, 0.f, 0.f, 0.f};
    #pragma unroll
    for (int dc = 0; dc < 32; dc += 4) {
        float4 f = *(const float4*)(fb + dc);
        #pragma unroll
        for (int h = 0; h < 8; ++h) {
            v[h] = fmaf(f.x, mb[h * 32 + dc], v[h]);
            v[h] = fmaf(f.y, mb[h * 32 + dc + 1], v[h]);
            v[h] = fmaf(f.z, mb[h * 32 + dc + 2], v[h]);
            v[h] = fmaf(f.w, mb[h * 32 + dc + 3], v[h]);
        }
    }
    if (valid) {
        #pragma unroll
        for (int h = 0; h < 8; ++h)
            cSb[(size_t)b * 2880 + h * NG + j] = v[h] * CS_SCALE;
    }
}

// gihxAll[t][n][b] via MFMA: M=2048 (Wih rows), cols = t*64+b, K=512. 1920 blocks.
__global__ __launch_bounds__(256) void kGihxMF(const unsigned short* __restrict__ Wihx,
                                               const unsigned short* __restrict__ xbf,
                                               float* __restrict__ gihxAll) {
    int wid = __builtin_amdgcn_readfirstlane((int)blockIdx.x * 4 + ((int)threadIdx.x >> 6));
    int lane = (int)threadIdx.x & 63;
    int mt = wid / 60, nt = wid % 60;
    int m0 = mt * 16, col = lane & 15, q = lane >> 4;
    const unsigned short* aB = Wihx + (size_t)(m0 + col) * 512 + q * 8;
    const unsigned short* bB = xbf + (size_t)(nt * 16 + col) * 512 + q * 8;
    f32x4 acc = {0.f, 0.f, 0.f, 0.f};
    #pragma unroll
    for (int kk = 0; kk < 16; ++kk) {
        bf16x8 af = *(const bf16x8*)(aB + kk * 32);
        bf16x8 bf = *(const bf16x8*)(bB + kk * 32);
        acc = __builtin_amdgcn_mfma_f32_16x16x32_bf16(af, bf, acc, 0, 0, 0);
    }
    int gcol = nt * 16 + col, t = gcol >> 6, b = gcol & 63;
    float* dst = gihxAll + (size_t)t * (4 * NU * 64);
    #pragma unroll
    for (int r = 0; r < 4; ++r) {
        int row = m0 + q * 4 + r;
        dst[row * 64 + b] = acc[r];
    }
}

// ---------- Per-step ----------

// LN(h_{t-1}) -> bf16 abf[b][512] (MFMA B layout) + leaky version into sbf rows.
__global__ __launch_bounds__(256) void kLN(
        const float* __restrict__ aT0, const float* __restrict__ hTall,
        const float* __restrict__ lnPS, const float* __restrict__ lnPQ,
        const float* __restrict__ ln_g, const float* __restrict__ ln_b,
        unsigned short* __restrict__ abf, unsigned short* __restrict__ sbf, int t) {
    __shared__ float tile[64 * 65];
    int tid = (int)threadIdx.x;
    int b = tid & 63, r = tid >> 6;
    int u0 = (int)blockIdx.x * 64;
    if (t > 0) {
        const float* pS = lnPS + (size_t)(t - 1) * 2048;
        const float* pQ = lnPQ + (size_t)(t - 1) * 2048;
        float ms = 0.f, qs = 0.f;
        #pragma unroll 8
        for (int i = 0; i < 32; ++i) { ms += pS[i * 64 + b]; qs += pQ[i * 64 + b]; }
        float m = ms * (1.f / 512.f);
        float var = qs * (1.f / 512.f) - m * m;
        float rstd = 1.f / sqrtf(var + 1e-5f);
        float mneg = -m * rstd;
        const float* src = hTall + (size_t)(t - 1) * (NU * 64);
        #pragma unroll
        for (int i = 0; i < 16; ++i) {
            int ul = r + i * 4;
            int u = u0 + ul;
            float x = src[u * 64 + b];
            tile[b * 65 + ul] = fmaf(fmaf(x, rstd, mneg), ln_g[u], ln_b[u]);
        }
    } else {
        #pragma unroll
        for (int i = 0; i < 16; ++i) {
            int ul = r + i * 4;
            tile[b * 65 + ul] = aT0[(u0 + ul) * 64 + b];
        }
    }
    __syncthreads();
    bool doS = t > 0;
    unsigned short* srow = sbf + (size_t)(t - 1) * 64 * NU;
    #pragma unroll
    for (int i = 0; i < 16; ++i) {
        int idx = tid + i * 256;
        int bb = idx >> 6, ul = idx & 63;
        float v = tile[bb * 65 + ul];
        abf[(size_t)bb * NU + u0 + ul] = f2bf(v);
        if (doS) srow[(size_t)bb * NU + u0 + ul] = f2bf(leaky(v));
    }
}

// MFMA: [qa(544); ghh(2048)] = WA[2592][512] · abf[64][512]^T. 162 blocks.
__global__ __launch_bounds__(256) void kAMF(
        const unsigned short* __restrict__ WA, const unsigned short* __restrict__ abf,
        const float* __restrict__ in_b,
        float* __restrict__ qaT, float* __restrict__ ghh) {
    int wid = __builtin_amdgcn_readfirstlane((int)blockIdx.x * 4 + ((int)threadIdx.x >> 6));
    int lane = (int)threadIdx.x & 63;
    int mt = wid >> 2, bt = wid & 3;
    int m0 = mt * 16, col = lane & 15, q = lane >> 4;
    const unsigned short* aB = WA + (size_t)(m0 + col) * NU + q * 8;
    const unsigned short* bB = abf + (size_t)(bt * 16 + col) * NU + q * 8;
    f32x4 acc = {0.f, 0.f, 0.f, 0.f};
    #pragma unroll
    for (int kk = 0; kk < 16; ++kk) {
        bf16x8 af = *(const bf16x8*)(aB + kk * 32);
        bf16x8 bf = *(const bf16x8*)(bB + kk * 32);
        acc = __builtin_amdgcn_mfma_f32_16x16x32_bf16(af, bf, acc, 0, 0, 0);
    }
    int b = bt * 16 + col;
    if (m0 < 544) {  // wave-uniform: 544 = 34 full tiles
        #pragma unroll
        for (int r = 0; r < 4; ++r) {
            int row = m0 + q * 4 + r;
            qaT[row * 64 + b] = acc[r] + in_b[row];
        }
    } else {
        #pragma unroll
        for (int r = 0; r < 4; ++r) {
            int row = m0 - 544 + q * 4 + r;
            ghh[row * 64 + b] = acc[r];
        }
    }
}

// Fused attention: m (was kM) + e/exp partials (was kB) + W/ctx (was kC).
// 64 blocks, one per b.
__global__ __launch_bounds__(256) void kAttn(
        const float* __restrict__ qa, const float* __restrict__ in_w,
        const float* __restrict__ featB, const float* __restrict__ cSb,
        float* __restrict__ out, float* __restrict__ ctx, int t) {
    __shared__ float mL[256];
    __shared__ float eL[8 * 384];
    __shared__ float cL[8 * 384];
    __shared__ float WL[360];
    __shared__ float redS[4][8], redC[4][8];
    __shared__ float SevL[8], CevL[8];
    __shared__ float cpart[256];
    int b = (int)blockIdx.x, tid = (int)threadIdx.x;
    int lane = tid & 63, w = tid >> 6;

    // phase 1: m[b][256] (identical math to old kM; qa reads are block-uniform)
    {
        int h = tid >> 5, c = tid & 31;
        float acc = 0.f;
        const float* wcol = in_w + (size_t)(NE + h * NHD) * NE + c;
        #pragma unroll 4
        for (int d = 0; d < NHD; ++d)
            acc = fmaf(qa[(h * NHD + d) * 64 + b], wcol[(size_t)d * NE], acc);
        mL[tid] = acc;
    }
    __syncthreads();

    // phase 2: per-j scores -> e, partial sums
    float eS[8] = {0.f, 0.f, 0.f, 0.f, 0.f, 0.f, 0.f, 0.f};
    float eC[8] = {0.f, 0.f, 0.f, 0.f, 0.f, 0.f, 0.f, 0.f};
    for (int j = tid; j < NG; j += 256) {
        const float* fb = featB + ((size_t)b * NG + j) * 32;
        float v[8] = {0.f, 0.f, 0.f, 0.f, 0.f, 0.f, 0.f, 0.f};
        #pragma unroll
        for (int dc = 0; dc < 32; dc += 4) {
            float4 f = *(const float4*)(fb + dc);
            #pragma unroll
            for (int h = 0; h < 8; ++h) {
                v[h] = fmaf(f.x, mL[h * 32 + dc], v[h]);
                v[h] = fmaf(f.y, mL[h * 32 + dc + 1], v[h]);
                v[h] = fmaf(f.z, mL[h * 32 + dc + 2], v[h]);
                v[h] = fmaf(f.w, mL[h * 32 + dc + 3], v[h]);
            }
        }
        #pragma unroll
        for (int h = 0; h < 8; ++h) {
            float e = expf(v[h] * INV_SQRT_HD);
            float c = cSb[(size_t)b * 2880 + h * NG + j];
            eL[h * 384 + j] = e;
            cL[h * 384 + j] = c;
            eS[h] += e;
            eC[h] += c * e;
        }
    }
    // phase 3: block reduction of eS/eC per h
    #pragma unroll
    for (int h = 0; h < 8; ++h) {
        #pragma unroll
        for (int off = 32; off > 0; off >>= 1) {
            eS[h] += __shfl_xor(eS[h], off);
            eC[h] += __shfl_xor(eC[h], off);
        }
    }
    if (lane == 0) {
        #pragma unroll
        for (int h = 0; h < 8; ++h) { redS[w][h] = eS[h]; redC[w][h] = eC[h]; }
    }
    __syncthreads();
    if (tid < 8) {
        float s = 0.f, c = 0.f;
        #pragma unroll
        for (int ww = 0; ww < 4; ++ww) { s += redS[ww][tid]; c += redC[ww][tid]; }
        SevL[tid] = s; CevL[tid] = c;
    }
    __syncthreads();
    float invS[8], cevM[8];
    #pragma unroll
    for (int h = 0; h < 8; ++h) {
        float iv = 1.f / SevL[h];
        invS[h] = iv;
        cevM[h] = CevL[h] * iv;
    }
    // phase 4: W per j, write scores
    for (int j = tid; j < NG; j += 256) {
        float acc = 0.f;
        #pragma unroll
        for (int h = 0; h < 8; ++h) {
            float e = eL[h * 384 + j];
            float c = cL[h * 384 + j];
            acc += e * invS[h] * (1.f + (c - cevM[h]) * (1.f / 360.f));
        }
        float W = acc * 0.125f;
        WL[j] = W;
        out[OFF_SCORES + (size_t)b * (NT * NG) + t * NG + j] = W;
    }
    __syncthreads();
    // phase 5: ctx[d][b]
    int d = tid & 31, sl = tid >> 5;
    float a = 0.f;
    for (int i = 0; i < 45; ++i) {
        int j = sl * 45 + i;
        a += WL[j] * featB[((size_t)b * NG + j) * 32 + d];
    }
    cpart[tid] = a;
    __syncthreads();
    if (tid < 32) {
        float s = 0.f;
        #pragma unroll
        for (int ss = 0; ss < 8; ++ss) s += cpart[ss * 32 + tid];
        ctx[tid * 64 + b] = s;
    }
}

// 32 blocks (16 u each): gates + cell + h + LN partials. ctx read directly.
__global__ __launch_bounds__(256) void kF1(
        const float* __restrict__ gihxT, const float* __restrict__ ghh,
        const float* __restrict__ ctx, const float* __restrict__ Wih,
        const float* __restrict__ bih, const float* __restrict__ bhh,
        float* __restrict__ cT, float* __restrict__ hDst,
        float* __restrict__ lnPS, float* __restrict__ lnPQ) {
    __shared__ float rS[256], rQ[256];
    int tid = (int)threadIdx.x, bid = (int)blockIdx.x;
    int lane = tid & 63, w = tid >> 6;
    float cx[32];
    #pragma unroll 8
    for (int d = 0; d < 32; ++d) cx[d] = ctx[d * 64 + lane];
    int u0 = bid * 16 + w * 4;
    float ssum = 0.f, qsum = 0.f;
    for (int i = 0; i < 4; ++i) {
        int u = u0 + i;
        float g4[4];
        #pragma unroll
        for (int q = 0; q < 4; ++q) {
            int n = q * NU + u;
            float gv = gihxT[n * 64 + lane] + ghh[n * 64 + lane] + bih[n] + bhh[n];
            const float* wr = Wih + (size_t)n * NE;
            #pragma unroll
            for (int d = 0; d < 32; ++d) gv += cx[d] * wr[d];
            g4[q] = gv;
        }
        float ig = sigm(g4[0]), fg = sigm(g4[1]), gg = tanhf(g4[2]), og = sigm(g4[3]);
        float cn = fg * cT[u * 64 + lane] + ig * gg;
        cT[u * 64 + lane] = cn;
        float hv = og * tanhf(cn);
        hDst[u * 64 + lane] = hv;
        ssum += hv; qsum += hv * hv;
    }
    rS[tid] = ssum; rQ[tid] = qsum;
    __syncthreads();
    if (tid < 64) {
        lnPS[bid * 64 + tid] = rS[tid] + rS[64 + tid] + rS[128 + tid] + rS[192 + tid];
        lnPQ[bid * 64 + tid] = rQ[tid] + rQ[64 + tid] + rQ[128 + tid] + rQ[192 + tid];
    }
}

// ---------- Post-loop head ----------

// MFMA: h1 = leaky(W1x·sbf^T + b1) packed bf16 into kLogitsMF B layout. 240 blocks.
__global__ __launch_bounds__(256) void kHeadMF(
        const unsigned short* __restrict__ W1x, const unsigned short* __restrict__ sbf,
        const float* __restrict__ b1, unsigned short* __restrict__ h1bf) {
    int wid = __builtin_amdgcn_readfirstlane((int)blockIdx.x * 4 + ((int)threadIdx.x >> 6));
    int lane = (int)threadIdx.x & 63;
    int mt = wid / 60, nt = wid % 60;
    int m0 = mt * 16, col = lane & 15, q = lane >> 4;
    const unsigned short* aB = W1x + (size_t)(m0 + col) * NU + q * 8;
    const unsigned short* bB = sbf + (size_t)(nt * 16 + col) * NU + q * 8;
    f32x4 acc = {0.f, 0.f, 0.f, 0.f};
    #pragma unroll
    for (int kk = 0; kk < 16; ++kk) {
        bf16x8 af = *(const bf16x8*)(aB + kk * 32);
        bf16x8 bf = *(const bf16x8*)(bB + kk * 32);
        acc = __builtin_amdgcn_mfma_f32_16x16x32_bf16(af, bf, acc, 0, 0, 0);
    }
    int gcol = nt * 16 + col;
    u16x4 pk;
    #pragma unroll
    for (int r = 0; r < 4; ++r) {
        float v = leaky(acc[r] + b1[m0 + q * 4 + r]);
        pk[r] = f2bf(v);
    }
    *(u16x4*)(h1bf + (size_t)gcol * 256 + m0 + q * 4) = pk;
}

// MFMA logits: 4695 blocks. Stores exp(logit) directly (softmax numerator).
__global__ __launch_bounds__(256) void kLogitsMF(const unsigned short* __restrict__ W2bf,
                                                 const unsigned short* __restrict__ h1bfT,
                                                 const float* __restrict__ b2,
                                                 float* __restrict__ lgAll, float* __restrict__ zPm) {
    int wid = __builtin_amdgcn_readfirstlane((int)blockIdx.x * 4 + ((int)threadIdx.x >> 6));
    int lane = (int)threadIdx.x & 63;
    int t = wid / 1252;
    int rem = wid - t * 1252;
    int mt = rem >> 2, ntile = rem & 3;
    int m0 = mt * 16, b0 = ntile * 16;
    int q = lane >> 4, col = lane & 15;
    const unsigned short* aBase = W2bf + (size_t)(m0 + col) * 256 + q * 8;
    const unsigned short* bBase = h1bfT + ((size_t)t * 64 + b0 + col) * 256 + q * 8;
    f32x4 acc = {0.f, 0.f, 0.f, 0.f};
    #pragma unroll
    for (int kk = 0; kk < 8; ++kk) {
        bf16x8 af = *(const bf16x8*)(aBase + kk * 32);
        bf16x8 bf = *(const bf16x8*)(bBase + kk * 32);
        acc = __builtin_amdgcn_mfma_f32_16x16x32_bf16(af, bf, acc, 0, 0, 0);
    }
    float eS = 0.f;
    #pragma unroll
    for (int r = 0; r < 4; ++r) {
        int row = m0 + q * 4 + r;
        if (row < NVOC) {
            float e = expf(acc[r] + b2[row]);
            lgAll[((size_t)t * NVOC + row) * 64 + b0 + col] = e;
            eS += e;
        }
    }
    eS += __shfl_xor(eS, 16);
    eS += __shfl_xor(eS, 32);
    if (lane < 16)
        zPm[((size_t)t * 313 + mt) * 64 + b0 + col] = eS;
}

// 15 blocks: full Z reduction per t, store 1/Z
__global__ __launch_bounds__(256) void kZinv(const float* __restrict__ zPm, float* __restrict__ zInv) {
    __shared__ float red[256];
    int t = (int)blockIdx.x, tid = (int)threadIdx.x;
    int lane = tid & 63, w = tid >> 6;
    float p = 0.f;
    for (int i = w; i < 313; i += 4) p += zPm[((size_t)t * 313 + i) * 64 + lane];
    red[tid] = p;
    __syncthreads();
    if (tid < 64) {
        float z = red[tid] + red[64 + tid] + red[128 + tid] + red[192 + tid];
        zInv[t * 64 + tid] = 1.f / z;
    }
}

__global__ __launch_bounds__(256) void kOut(const float* __restrict__ lgAll,
                                            const float* __restrict__ zInv, float* __restrict__ out) {
    __shared__ float tile[64 * 65];
    int bid = (int)blockIdx.x;
    int t = bid / 79, nt = bid % 79;
    int n0 = nt * 64;
    int tid = (int)threadIdx.x, lane = tid & 63, w = tid >> 6;
    const float* lg = lgAll + (size_t)t * (NVOC * 64);
    float invZ = zInv[t * 64 + lane];
    for (int i = 0; i < 16; ++i) {
        int r = w * 16 + i, n = n0 + r;
        if (n < NVOC) tile[r * 65 + lane] = lg[n * 64 + lane] * invZ;
    }
    __syncthreads();
    for (int i = 0; i < 16; ++i) {
        int b = w * 16 + i;
        int n = n0 + lane;
        if (n < NVOC) out[(size_t)b * (NT * NVOC) + t * NVOC + n] = tile[lane * 65 + b];
    }
}

// ---------- Launch ----------
extern "C" void kernel_launch(void* const* d_in, const int* in_sizes, int n_in,
                              void* d_out, int out_size, void* d_ws, size_t ws_size,
                              hipStream_t stream) {
    const float* features = (const float*)d_in[0];
    const int*   text     = (const int*)d_in[1];
    const float* a0       = (const float*)d_in[2];
    const float* c0       = (const float*)d_in[3];
    const float* enc_W    = (const float*)d_in[4];
    const float* enc_b    = (const float*)d_in[5];
    const float* enc_g    = (const float*)d_in[6];
    const float* enc_beta = (const float*)d_in[7];
    const float* emb      = (const float*)d_in[8];
    const float* in_w     = (const float*)d_in[9];
    const float* in_b     = (const float*)d_in[10];
    const float* Wih      = (const float*)d_in[11];
    const float* Whh      = (const float*)d_in[12];
    const float* bih      = (const float*)d_in[13];
    const float* bhh      = (const float*)d_in[14];
    const float* ln_g     = (const float*)d_in[15];
    const float* ln_b     = (const float*)d_in[16];
    const float* W1       = (const float*)d_in[17];
    const float* b1       = (const float*)d_in[18];
    const float* W2       = (const float*)d_in[19];
    const float* b2       = (const float*)d_in[20];
    float* out = (float*)d_out;

    float* ws = (float*)d_ws;
    size_t off = 0;
    auto alloc = [&](size_t n) { float* p = ws + off; off += (n + 63) & ~(size_t)63; return p; };
    float* lgAll   = alloc((size_t)NT * NVOC * 64);   // aliased as fX pre-loop
    float* fX      = lgAll;
    float* featT   = alloc((size_t)NG * ND * 64);
    float* featB   = alloc((size_t)64 * NG * ND);
    float* gihxAll = alloc((size_t)NT * 4 * NU * 64);
    float* fmean   = alloc((size_t)ND * 64);
    float* qmean   = alloc((size_t)NE * 64);
    float* mq      = alloc((size_t)64 * 256);
    float* cSb     = alloc((size_t)64 * NH * NG);
    float* aT0     = alloc((size_t)NU * 64);
    float* cT_     = alloc((size_t)NU * 64);
    float* hTall   = alloc((size_t)NT * NU * 64);
    float* qaT     = alloc((size_t)NE * 64);
    float* ghh     = alloc((size_t)4 * NU * 64);
    float* ctx     = alloc((size_t)ND * 64);
    float* lnPS    = alloc((size_t)NT * 32 * 64);
    float* lnPQ    = alloc((size_t)NT * 32 * 64);
    float* zPm     = alloc((size_t)NT * 313 * 64);
    float* zInv    = alloc((size_t)NT * 64);
    unsigned short* WA   = (unsigned short*)alloc((size_t)2592 * 256);  // [2592][512] bf16: Wq rows 0..543, Whh rows 544..2591
    unsigned short* W1x  = (unsigned short*)alloc((size_t)256 * 256);   // [256][512] bf16
    unsigned short* abf  = (unsigned short*)alloc((size_t)64 * 256);    // [64][512] bf16, per-step a=LN(h)
    unsigned short* sbf  = (unsigned short*)alloc((size_t)960 * 256);   // [960][512] bf16, leaky(LN(h_t)) all t
    unsigned short* Wihx = (unsigned short*)alloc((size_t)2048 * 256);
    unsigned short* xbf  = (unsigned short*)alloc((size_t)960 * 256);
    unsigned short* W2bf = (unsigned short*)alloc((size_t)5008 * 128);
    unsigned short* h1bf = (unsigned short*)alloc((size_t)NT * 64 * 128);  // [960][256] bf16

    // weight prep
    kCvt<<<1088, 256, 0, stream>>>(in_w, NE, ND, 512, 544 * 512, WA);
    kCvt<<<4096, 256, 0, stream>>>(Whh, NU, 0, 512, 2048 * 512, WA + (size_t)544 * 512);
    kCvt<<<512, 256, 0, stream>>>(W1, NU, 0, 512, 256 * 512, W1x);
    kCvt<<<4096, 256, 0, stream>>>(Wih, NE, ND, 512, 2048 * 512, Wihx);
    kCvtW2<<<5008, 256, 0, stream>>>(W2, W2bf);

    // precompute
    k_transpose_feat<<<563, 256, 0, stream>>>(features, fX);
    k_encoder2<<<NG, 256, 0, stream>>>(fX, enc_W, enc_b, enc_g, enc_beta, featT, featB);
    k_init_state<<<16, 256, 0, stream>>>(a0, c0, aT0, cT_);
    kEmbed<<<NT, 256, 0, stream>>>(text, emb, xbf);
    k_featmean<<<8, 256, 0, stream>>>(featT, fmean);
    k_qmean<<<17, 256, 0, stream>>>(fmean, in_w, qmean);
    kM<<<8, 256, 0, stream>>>(qmean, in_w, mq);
    kCS<<<96, 256, 0, stream>>>(mq, featB, cSb);
    kGihxMF<<<1920, 256, 0, stream>>>(Wihx, xbf, gihxAll);

    for (int t = 0; t < NT; ++t) {
        kLN<<<8, 256, 0, stream>>>(aT0, hTall, lnPS, lnPQ, ln_g, ln_b, abf, sbf, t);
        kAMF<<<162, 256, 0, stream>>>(WA, abf, in_b, qaT, ghh);
        kAttn<<<64, 256, 0, stream>>>(qaT, in_w, featB, cSb, out, ctx, t);
        kF1<<<32, 256, 0, stream>>>(gihxAll + (size_t)t * 4 * NU * 64, ghh, ctx, Wih,
                                    bih, bhh, cT_, hTall + (size_t)t * NU * 64,
                                    lnPS + (size_t)t * 2048, lnPQ + (size_t)t * 2048);
    }

    // final LN (h_14 -> sbf rows 14*64..) then MFMA head
    kLN<<<8, 256, 0, stream>>>(aT0, hTall, lnPS, lnPQ, ln_g, ln_b, abf, sbf, NT);
    kHeadMF<<<240, 256, 0, stream>>>(W1x, sbf, b1, h1bf);
    kLogitsMF<<<4695, 256, 0, stream>>>(W2bf, h1bf, b2, lgAll, zPm);
    kZinv<<<NT, 256, 0, stream>>>(zPm, zInv);
    kOut<<<NT * 79, 256, 0, stream>>>(lgAll, zInv, out);
}

// Round 3
// 729.108 us; speedup vs baseline: 1.9943x; 1.3002x over previous
//
#include <hip/hip_runtime.h>
#include <math.h>

#define NG 360
#define NV 100
#define ND 32
#define NU 512
#define NT 15
#define NVOC 5000
#define NH 8
#define NE 544
#define NHD 68
#define OFF_SCORES 4800000
#define INV_SQRT_HD 0.12126781f
#define CS_SCALE 43.65636f

typedef short bf16x8 __attribute__((ext_vector_type(8)));
typedef float f32x4 __attribute__((ext_vector_type(4)));
typedef unsigned short u16x4 __attribute__((ext_vector_type(4)));

__device__ __forceinline__ float leaky(float x) { return x >= 0.f ? x : 0.2f * x; }
__device__ __forceinline__ float sigm(float x) { return 1.f / (1.f + expf(-x)); }
__device__ __forceinline__ unsigned short f2bf(float x) {
    unsigned b = __float_as_uint(x);
    return (unsigned short)((b + 0x7FFFu + ((b >> 16) & 1u)) >> 16);
}

// ---------- Weight prep ----------

// plain bf16 row-major [rows][K] from fp32 (ldw stride, col0 offset)
__global__ __launch_bounds__(256) void kCvt(const float* __restrict__ W, int ldw, int col0,
                                            int K, int total, unsigned short* __restrict__ o) {
    int idx = (int)blockIdx.x * 256 + (int)threadIdx.x;
    if (idx >= total) return;
    int r = idx / K, k = idx - r * K;
    o[idx] = f2bf(W[(size_t)r * ldw + col0 + k]);
}

// W2 -> bf16 [5008][256] (8 pad rows zeroed)
__global__ __launch_bounds__(256) void kCvtW2(const float* __restrict__ W2,
                                              unsigned short* __restrict__ W2bf) {
    int idx = (int)blockIdx.x * 256 + (int)threadIdx.x;
    if (idx < NVOC * 256) W2bf[idx] = f2bf(W2[idx]);
    else if (idx < 5008 * 256) W2bf[idx] = 0;
}

// Wc[n][d] = Wih[n][d] for d<32 (ctx columns, packed fp32)
__global__ __launch_bounds__(256) void kCvtWc(const float* __restrict__ Wih,
                                              float* __restrict__ Wc) {
    int idx = (int)blockIdx.x * 256 + (int)threadIdx.x;
    if (idx >= 2048 * 32) return;
    int r = idx >> 5, d = idx & 31;
    Wc[idx] = Wih[(size_t)r * NE + d];
}

// ---------- Precompute ----------

__global__ void k_transpose_feat(const float* __restrict__ features, float* __restrict__ fX) {
    __shared__ float tile[64 * 65];
    int c0 = (int)blockIdx.x * 64;
    int tl = (int)threadIdx.x;
    int c = tl & 63, q0 = tl >> 6;
    for (int i = 0; i < 16; ++i) {
        int b = q0 + (i << 2);
        int col = c0 + c;
        float v = (col < NG * NV) ? features[b * (NG * NV) + col] : 0.f;
        tile[c * 65 + b] = v;
    }
    __syncthreads();
    int b2 = tl & 63, cr = tl >> 6;
    for (int i = 0; i < 16; ++i) {
        int c2 = cr + (i << 2);
        int col = c0 + c2;
        if (col < NG * NV) fX[col * 64 + b2] = tile[c2 * 65 + b2];
    }
}

// encoder: writes featT [(g*32+d)][b] and featB [b][g][d]
__global__ __launch_bounds__(256) void k_encoder2(
        const float* __restrict__ fX, const float* __restrict__ enc_W,
        const float* __restrict__ enc_b, const float* __restrict__ enc_g,
        const float* __restrict__ enc_beta, float* __restrict__ featT,
        float* __restrict__ featB) {
    __shared__ float fxs[6400];
    __shared__ float ps[256], pq[256];
    int g = (int)blockIdx.x, tid = (int)threadIdx.x;
    #pragma unroll
    for (int k = 0; k < 25; ++k) fxs[tid + k * 256] = fX[g * 6400 + tid + k * 256];
    __syncthreads();
    int lane = tid & 63, w = tid >> 6, d0 = w * 8;
    float acc[8];
    #pragma unroll
    for (int j = 0; j < 8; ++j) acc[j] = enc_b[g * 32 + d0 + j];
    const float* wb = enc_W + g * 3200 + d0 * 100;
    #pragma unroll 4
    for (int v = 0; v < 100; ++v) {
        float fv = fxs[v * 64 + lane];
        #pragma unroll
        for (int j = 0; j < 8; ++j) acc[j] += fv * wb[j * 100 + v];
    }
    float sm = 0.f, sq = 0.f;
    #pragma unroll
    for (int j = 0; j < 8; ++j) { sm += acc[j]; sq += acc[j] * acc[j]; }
    ps[tid] = sm; pq[tid] = sq;
    __syncthreads();
    float m = (ps[lane] + ps[64 + lane] + ps[128 + lane] + ps[192 + lane]) * (1.f / 32.f);
    float q = (pq[lane] + pq[64 + lane] + pq[128 + lane] + pq[192 + lane]);
    float var = q * (1.f / 32.f) - m * m;
    float rstd = 1.f / sqrtf(var + 1e-5f);
    #pragma unroll
    for (int j = 0; j < 8; ++j) {
        int d = d0 + j;
        float x = (acc[j] - m) * rstd * enc_g[d] + enc_beta[d];
        x = leaky(x);
        featT[(g * 32 + d) * 64 + lane] = x;
        featB[((size_t)lane * NG + g) * 32 + d] = x;
    }
}

// abf[b][u] = bf16(a0[b][u]); cT[b][u] = c0[b][u]. 128 blocks.
__global__ __launch_bounds__(256) void kInit(const float* __restrict__ a0,
                                             const float* __restrict__ c0,
                                             unsigned short* __restrict__ abf,
                                             float* __restrict__ cT) {
    int idx = (int)blockIdx.x * 256 + (int)threadIdx.x;
    abf[idx] = f2bf(a0[idx]);
    cT[idx] = c0[idx];
}

// xbf[(t*64+b)][u] bf16
__global__ void kEmbed(const int* __restrict__ text, const float* __restrict__ emb,
                       unsigned short* __restrict__ xbf) {
    int t = (int)blockIdx.x, tid = (int)threadIdx.x;
    int b = tid >> 2, seg = (tid & 3) * 128;
    int row = text[b * NT + t];
    const float* er = emb + (size_t)row * NU;
    unsigned short* dst = xbf + ((size_t)t * 64 + b) * 512;
    for (int i = 0; i < 128; ++i) dst[seg + i] = f2bf(er[seg + i]);
}

__global__ void k_featmean(const float* __restrict__ featT, float* __restrict__ fmean) {
    int wid = __builtin_amdgcn_readfirstlane((int)blockIdx.x * 4 + ((int)threadIdx.x >> 6));
    int lane = (int)threadIdx.x & 63;
    if (wid >= ND) return;
    float s = 0.f;
    for (int g = 0; g < NG; ++g) s += featT[(g * ND + wid) * 64 + lane];
    fmean[wid * 64 + lane] = s * (1.f / 360.f);
}

__global__ void k_qmean(const float* __restrict__ fmean, const float* __restrict__ in_w,
                        float* __restrict__ qmean) {
    int wid = __builtin_amdgcn_readfirstlane((int)blockIdx.x * 4 + ((int)threadIdx.x >> 6));
    int lane = (int)threadIdx.x & 63;
    if (wid >= 68) return;
    int e0 = wid * 8;
    float acc[8];
    #pragma unroll
    for (int jj = 0; jj < 8; ++jj) acc[jj] = 0.f;
    #pragma unroll 4
    for (int d = 0; d < ND; ++d) {
        float fv = fmean[d * 64 + lane];
        #pragma unroll
        for (int jj = 0; jj < 8; ++jj) acc[jj] += fv * in_w[(e0 + jj) * NE + d];
    }
    #pragma unroll
    for (int jj = 0; jj < 8; ++jj) qmean[(e0 + jj) * 64 + lane] = acc[jj];
}

// m[b][h*32+d'] = sum_{d<68} Wk[h*68+d][d'] * qa[(h*68+d)][b]   (pre-loop only)
__global__ __launch_bounds__(256) void kM(const float* __restrict__ qa,
                                          const float* __restrict__ in_w,
                                          float* __restrict__ m) {
    int wid = __builtin_amdgcn_readfirstlane((int)blockIdx.x * 4 + ((int)threadIdx.x >> 6));
    int lane = (int)threadIdx.x & 63;
    int h = wid >> 2, dg = (wid & 3) * 8;
    float acc[8] = {0.f, 0.f, 0.f, 0.f, 0.f, 0.f, 0.f, 0.f};
    for (int d = 0; d < NHD; ++d) {
        float qv = qa[(h * NHD + d) * 64 + lane];
        const float* wr = in_w + (size_t)(NE + h * NHD + d) * NE + dg;
        #pragma unroll
        for (int i = 0; i < 8; ++i) acc[i] = fmaf(qv, wr[i], acc[i]);
    }
    #pragma unroll
    for (int i = 0; i < 8; ++i) m[(size_t)lane * 256 + h * 32 + dg + i] = acc[i];
}

// cSb[b][h][j] = CS_SCALE * feat[b,j]·mq[b,h]   (96 blocks, lane = j)
__global__ __launch_bounds__(256) void kCS(const float* __restrict__ mq,
                                           const float* __restrict__ featB,
                                           float* __restrict__ cSb) {
    int wid = __builtin_amdgcn_readfirstlane((int)blockIdx.x * 4 + ((int)threadIdx.x >> 6));
    int lane = (int)threadIdx.x & 63;
    int b = wid / 6, jt = wid % 6;
    int j = jt * 64 + lane;
    bool valid = j < NG;
    int jc = valid ? j : 0;
    const float* mb = mq + (size_t)b * 256;
    const float* fb = featB + ((size_t)b * NG + jc) * 32;
    float v[8] = {0.f, 0.f, 0.f, 0.f, 0.f, 0.f, 0.f, 0.f};
    #pragma unroll
    for (int dc = 0; dc < 32; dc += 4) {
        float4 f = *(const float4*)(fb + dc);
        #pragma unroll
        for (int h = 0; h < 8; ++h) {
            v[h] = fmaf(f.x, mb[h * 32 + dc], v[h]);
            v[h] = fmaf(f.y, mb[h * 32 + dc + 1], v[h]);
            v[h] = fmaf(f.z, mb[h * 32 + dc + 2], v[h]);
            v[h] = fmaf(f.w, mb[h * 32 + dc + 3], v[h]);
        }
    }
    if (valid) {
        #pragma unroll
        for (int h = 0; h < 8; ++h)
            cSb[(size_t)b * 2880 + h * NG + j] = v[h] * CS_SCALE;
    }
}

// gihxAll[t][b][n] via MFMA (bias folded): M=2048 (Wih rows), cols = t*64+b, K=512.
__global__ __launch_bounds__(256) void kGihxMF(const unsigned short* __restrict__ Wihx,
                                               const unsigned short* __restrict__ xbf,
                                               const float* __restrict__ bih,
                                               const float* __restrict__ bhh,
                                               float* __restrict__ gihxAll) {
    int wid = __builtin_amdgcn_readfirstlane((int)blockIdx.x * 4 + ((int)threadIdx.x >> 6));
    int lane = (int)threadIdx.x & 63;
    int mt = wid / 60, nt = wid % 60;
    int m0 = mt * 16, col = lane & 15, q = lane >> 4;
    const unsigned short* aB = Wihx + (size_t)(m0 + col) * 512 + q * 8;
    const unsigned short* bB = xbf + (size_t)(nt * 16 + col) * 512 + q * 8;
    f32x4 acc = {0.f, 0.f, 0.f, 0.f};
    #pragma unroll
    for (int kk = 0; kk < 16; ++kk) {
        bf16x8 af = *(const bf16x8*)(aB + kk * 32);
        bf16x8 bf = *(const bf16x8*)(bB + kk * 32);
        acc = __builtin_amdgcn_mfma_f32_16x16x32_bf16(af, bf, acc, 0, 0, 0);
    }
    int gcol = nt * 16 + col, t = gcol >> 6, b = gcol & 63;
    int n0 = m0 + q * 4;
    float4 o;
    o.x = acc[0] + bih[n0] + bhh[n0];
    o.y = acc[1] + bih[n0 + 1] + bhh[n0 + 1];
    o.z = acc[2] + bih[n0 + 2] + bhh[n0 + 2];
    o.w = acc[3] + bih[n0 + 3] + bhh[n0 + 3];
    *(float4*)(gihxAll + ((size_t)(t * 64 + b)) * 2048 + n0) = o;
}

// ---------- Per-step ----------

// MFMA: [qa(544); ghhT(2048)] = WA[2592][512] · abf[64][512]^T. 162 blocks.
// qa written [n][64+b]; ghh written transposed [b][2048].
__global__ __launch_bounds__(256) void kAMF(
        const unsigned short* __restrict__ WA, const unsigned short* __restrict__ abf,
        const float* __restrict__ in_b,
        float* __restrict__ qaT, float* __restrict__ ghhT) {
    int wid = __builtin_amdgcn_readfirstlane((int)blockIdx.x * 4 + ((int)threadIdx.x >> 6));
    int lane = (int)threadIdx.x & 63;
    int mt = wid >> 2, bt = wid & 3;
    int m0 = mt * 16, col = lane & 15, q = lane >> 4;
    const unsigned short* aB = WA + (size_t)(m0 + col) * NU + q * 8;
    const unsigned short* bB = abf + (size_t)(bt * 16 + col) * NU + q * 8;
    f32x4 acc = {0.f, 0.f, 0.f, 0.f};
    #pragma unroll
    for (int kk = 0; kk < 16; ++kk) {
        bf16x8 af = *(const bf16x8*)(aB + kk * 32);
        bf16x8 bf = *(const bf16x8*)(bB + kk * 32);
        acc = __builtin_amdgcn_mfma_f32_16x16x32_bf16(af, bf, acc, 0, 0, 0);
    }
    int b = bt * 16 + col;
    if (m0 < 544) {  // wave-uniform: 544 = 34 full tiles
        #pragma unroll
        for (int r = 0; r < 4; ++r) {
            int row = m0 + q * 4 + r;
            qaT[row * 64 + b] = acc[r] + in_b[row];
        }
    } else {
        int n0 = m0 - 544 + q * 4;
        float4 o; o.x = acc[0]; o.y = acc[1]; o.z = acc[2]; o.w = acc[3];
        *(float4*)(ghhT + (size_t)b * 2048 + n0) = o;
    }
}

// Fused step: attention (m + scores + softmax combine + ctx in LDS) then
// LSTM gates + cell + h + full LN + emit abf (next step) and sbf (head).
// 64 blocks, one per b.
__global__ __launch_bounds__(256) void kStep(
        const float* __restrict__ qa, const float* __restrict__ in_w,
        const float* __restrict__ featB, const float* __restrict__ cSb,
        const float* __restrict__ gihxT, const float* __restrict__ ghhT,
        const float* __restrict__ Wc,
        const float* __restrict__ ln_g, const float* __restrict__ ln_b,
        float* __restrict__ cT,
        unsigned short* __restrict__ abf, unsigned short* __restrict__ sbf,
        float* __restrict__ out, int t) {
    __shared__ float mL[256];
    __shared__ float eL[8 * 384];
    __shared__ float cL[8 * 384];
    __shared__ float WL[360];
    __shared__ float redS[4][8], redC[4][8];
    __shared__ float SevL[8], CevL[8];
    __shared__ float cpart[256];
    __shared__ float ctxL[32];
    int b = (int)blockIdx.x, tid = (int)threadIdx.x;
    int lane = tid & 63, w = tid >> 6;

    // phase 1: m[b][256]
    {
        int h = tid >> 5, c = tid & 31;
        float acc = 0.f;
        const float* wcol = in_w + (size_t)(NE + h * NHD) * NE + c;
        #pragma unroll 4
        for (int d = 0; d < NHD; ++d)
            acc = fmaf(qa[(h * NHD + d) * 64 + b], wcol[(size_t)d * NE], acc);
        mL[tid] = acc;
    }
    __syncthreads();

    // phase 2: per-j scores -> e, partial sums
    float eS[8] = {0.f, 0.f, 0.f, 0.f, 0.f, 0.f, 0.f, 0.f};
    float eC[8] = {0.f, 0.f, 0.f, 0.f, 0.f, 0.f, 0.f, 0.f};
    for (int j = tid; j < NG; j += 256) {
        const float* fb = featB + ((size_t)b * NG + j) * 32;
        float v[8] = {0.f, 0.f, 0.f, 0.f, 0.f, 0.f, 0.f, 0.f};
        #pragma unroll
        for (int dc = 0; dc < 32; dc += 4) {
            float4 f = *(const float4*)(fb + dc);
            #pragma unroll
            for (int h = 0; h < 8; ++h) {
                v[h] = fmaf(f.x, mL[h * 32 + dc], v[h]);
                v[h] = fmaf(f.y, mL[h * 32 + dc + 1], v[h]);
                v[h] = fmaf(f.z, mL[h * 32 + dc + 2], v[h]);
                v[h] = fmaf(f.w, mL[h * 32 + dc + 3], v[h]);
            }
        }
        #pragma unroll
        for (int h = 0; h < 8; ++h) {
            float e = expf(v[h] * INV_SQRT_HD);
            float c = cSb[(size_t)b * 2880 + h * NG + j];
            eL[h * 384 + j] = e;
            cL[h * 384 + j] = c;
            eS[h] += e;
            eC[h] += c * e;
        }
    }
    // phase 3: block reduction per h
    #pragma unroll
    for (int h = 0; h < 8; ++h) {
        #pragma unroll
        for (int off = 32; off > 0; off >>= 1) {
            eS[h] += __shfl_xor(eS[h], off);
            eC[h] += __shfl_xor(eC[h], off);
        }
    }
    if (lane == 0) {
        #pragma unroll
        for (int h = 0; h < 8; ++h) { redS[w][h] = eS[h]; redC[w][h] = eC[h]; }
    }
    __syncthreads();
    if (tid < 8) {
        float s = 0.f, c = 0.f;
        #pragma unroll
        for (int ww = 0; ww < 4; ++ww) { s += redS[ww][tid]; c += redC[ww][tid]; }
        SevL[tid] = s; CevL[tid] = c;
    }
    __syncthreads();
    float invS[8], cevM[8];
    #pragma unroll
    for (int h = 0; h < 8; ++h) {
        float iv = 1.f / SevL[h];
        invS[h] = iv;
        cevM[h] = CevL[h] * iv;
    }
    // phase 4: W per j, write scores
    for (int j = tid; j < NG; j += 256) {
        float acc = 0.f;
        #pragma unroll
        for (int h = 0; h < 8; ++h) {
            float e = eL[h * 384 + j];
            float c = cL[h * 384 + j];
            acc += e * invS[h] * (1.f + (c - cevM[h]) * (1.f / 360.f));
        }
        float W = acc * 0.125f;
        WL[j] = W;
        out[OFF_SCORES + (size_t)b * (NT * NG) + t * NG + j] = W;
    }
    __syncthreads();
    // phase 5: ctx -> LDS
    {
        int d = tid & 31, sl = tid >> 5;
        float a = 0.f;
        for (int i = 0; i < 45; ++i) {
            int j = sl * 45 + i;
            a += WL[j] * featB[((size_t)b * NG + j) * 32 + d];
        }
        cpart[tid] = a;
    }
    __syncthreads();
    if (tid < 32) {
        float s = 0.f;
        #pragma unroll
        for (int ss = 0; ss < 8; ++ss) s += cpart[ss * 32 + tid];
        ctxL[tid] = s;
    }
    __syncthreads();

    // phase 6: gates + cell + h (u = tid, tid+256)
    const float* gihxB = gihxT + (size_t)b * 2048;
    const float* ghhB  = ghhT + (size_t)b * 2048;
    float* cB = cT + (size_t)b * 512;
    float hv[2];
    float ssum = 0.f, qsum = 0.f;
    #pragma unroll
    for (int ii = 0; ii < 2; ++ii) {
        int u = tid + ii * 256;
        float g4[4];
        #pragma unroll
        for (int q = 0; q < 4; ++q) {
            int n = q * 512 + u;
            float gv = gihxB[n] + ghhB[n];
            const float* wr = Wc + (size_t)n * 32;
            #pragma unroll
            for (int d = 0; d < 32; d += 4) {
                float4 f = *(const float4*)(wr + d);
                gv = fmaf(ctxL[d], f.x, gv);
                gv = fmaf(ctxL[d + 1], f.y, gv);
                gv = fmaf(ctxL[d + 2], f.z, gv);
                gv = fmaf(ctxL[d + 3], f.w, gv);
            }
            g4[q] = gv;
        }
        float ig = sigm(g4[0]), fg = sigm(g4[1]), gg = tanhf(g4[2]), og = sigm(g4[3]);
        float cn = fg * cB[u] + ig * gg;
        cB[u] = cn;
        hv[ii] = og * tanhf(cn);
        ssum += hv[ii]; qsum += hv[ii] * hv[ii];
    }
    // phase 7: LN over 512 h values (in-block)
    #pragma unroll
    for (int off = 32; off > 0; off >>= 1) {
        ssum += __shfl_xor(ssum, off);
        qsum += __shfl_xor(qsum, off);
    }
    if (lane == 0) { cpart[w] = ssum; cpart[8 + w] = qsum; }
    __syncthreads();
    float ms = cpart[0] + cpart[1] + cpart[2] + cpart[3];
    float qs = cpart[8] + cpart[9] + cpart[10] + cpart[11];
    float m = ms * (1.f / 512.f);
    float var = qs * (1.f / 512.f) - m * m;
    float rstd = 1.f / sqrtf(var + 1e-5f);
    float mneg = -m * rstd;
    unsigned short* srow = sbf + ((size_t)t * 64 + b) * 512;
    #pragma unroll
    for (int ii = 0; ii < 2; ++ii) {
        int u = tid + ii * 256;
        float aval = fmaf(fmaf(hv[ii], rstd, mneg), ln_g[u], ln_b[u]);
        abf[(size_t)b * 512 + u] = f2bf(aval);
        srow[u] = f2bf(leaky(aval));
    }
}

// ---------- Post-loop head ----------

// MFMA: h1 = leaky(W1x·sbf^T + b1) packed bf16 into kLogitsMF B layout. 240 blocks.
__global__ __launch_bounds__(256) void kHeadMF(
        const unsigned short* __restrict__ W1x, const unsigned short* __restrict__ sbf,
        const float* __restrict__ b1, unsigned short* __restrict__ h1bf) {
    int wid = __builtin_amdgcn_readfirstlane((int)blockIdx.x * 4 + ((int)threadIdx.x >> 6));
    int lane = (int)threadIdx.x & 63;
    int mt = wid / 60, nt = wid % 60;
    int m0 = mt * 16, col = lane & 15, q = lane >> 4;
    const unsigned short* aB = W1x + (size_t)(m0 + col) * NU + q * 8;
    const unsigned short* bB = sbf + (size_t)(nt * 16 + col) * NU + q * 8;
    f32x4 acc = {0.f, 0.f, 0.f, 0.f};
    #pragma unroll
    for (int kk = 0; kk < 16; ++kk) {
        bf16x8 af = *(const bf16x8*)(aB + kk * 32);
        bf16x8 bf = *(const bf16x8*)(bB + kk * 32);
        acc = __builtin_amdgcn_mfma_f32_16x16x32_bf16(af, bf, acc, 0, 0, 0);
    }
    int gcol = nt * 16 + col;
    u16x4 pk;
    #pragma unroll
    for (int r = 0; r < 4; ++r) {
        float v = leaky(acc[r] + b1[m0 + q * 4 + r]);
        pk[r] = f2bf(v);
    }
    *(u16x4*)(h1bf + (size_t)gcol * 256 + m0 + q * 4) = pk;
}

// MFMA logits: 4695 blocks. Stores exp(logit) directly (softmax numerator).
__global__ __launch_bounds__(256) void kLogitsMF(const unsigned short* __restrict__ W2bf,
                                                 const unsigned short* __restrict__ h1bfT,
                                                 const float* __restrict__ b2,
                                                 float* __restrict__ lgAll, float* __restrict__ zPm) {
    int wid = __builtin_amdgcn_readfirstlane((int)blockIdx.x * 4 + ((int)threadIdx.x >> 6));
    int lane = (int)threadIdx.x & 63;
    int t = wid / 1252;
    int rem = wid - t * 1252;
    int mt = rem >> 2, ntile = rem & 3;
    int m0 = mt * 16, b0 = ntile * 16;
    int q = lane >> 4, col = lane & 15;
    const unsigned short* aBase = W2bf + (size_t)(m0 + col) * 256 + q * 8;
    const unsigned short* bBase = h1bfT + ((size_t)t * 64 + b0 + col) * 256 + q * 8;
    f32x4 acc = {0.f, 0.f, 0.f, 0.f};
    #pragma unroll
    for (int kk = 0; kk < 8; ++kk) {
        bf16x8 af = *(const bf16x8*)(aBase + kk * 32);
        bf16x8 bf = *(const bf16x8*)(bBase + kk * 32);
        acc = __builtin_amdgcn_mfma_f32_16x16x32_bf16(af, bf, acc, 0, 0, 0);
    }
    float eS = 0.f;
    #pragma unroll
    for (int r = 0; r < 4; ++r) {
        int row = m0 + q * 4 + r;
        if (row < NVOC) {
            float e = expf(acc[r] + b2[row]);
            lgAll[((size_t)t * NVOC + row) * 64 + b0 + col] = e;
            eS += e;
        }
    }
    eS += __shfl_xor(eS, 16);
    eS += __shfl_xor(eS, 32);
    if (lane < 16)
        zPm[((size_t)t * 313 + mt) * 64 + b0 + col] = eS;
}

// 15 blocks: full Z reduction per t, store 1/Z
__global__ __launch_bounds__(256) void kZinv(const float* __restrict__ zPm, float* __restrict__ zInv) {
    __shared__ float red[256];
    int t = (int)blockIdx.x, tid = (int)threadIdx.x;
    int lane = tid & 63, w = tid >> 6;
    float p = 0.f;
    for (int i = w; i < 313; i += 4) p += zPm[((size_t)t * 313 + i) * 64 + lane];
    red[tid] = p;
    __syncthreads();
    if (tid < 64) {
        float z = red[tid] + red[64 + tid] + red[128 + tid] + red[192 + tid];
        zInv[t * 64 + tid] = 1.f / z;
    }
}

__global__ __launch_bounds__(256) void kOut(const float* __restrict__ lgAll,
                                            const float* __restrict__ zInv, float* __restrict__ out) {
    __shared__ float tile[64 * 65];
    int bid = (int)blockIdx.x;
    int t = bid / 79, nt = bid % 79;
    int n0 = nt * 64;
    int tid = (int)threadIdx.x, lane = tid & 63, w = tid >> 6;
    const float* lg = lgAll + (size_t)t * (NVOC * 64);
    float invZ = zInv[t * 64 + lane];
    for (int i = 0; i < 16; ++i) {
        int r = w * 16 + i, n = n0 + r;
        if (n < NVOC) tile[r * 65 + lane] = lg[n * 64 + lane] * invZ;
    }
    __syncthreads();
    for (int i = 0; i < 16; ++i) {
        int b = w * 16 + i;
        int n = n0 + lane;
        if (n < NVOC) out[(size_t)b * (NT * NVOC) + t * NVOC + n] = tile[lane * 65 + b];
    }
}

// ---------- Launch ----------
extern "C" void kernel_launch(void* const* d_in, const int* in_sizes, int n_in,
                              void* d_out, int out_size, void* d_ws, size_t ws_size,
                              hipStream_t stream) {
    const float* features = (const float*)d_in[0];
    const int*   text     = (const int*)d_in[1];
    const float* a0       = (const float*)d_in[2];
    const float* c0       = (const float*)d_in[3];
    const float* enc_W    = (const float*)d_in[4];
    const float* enc_b    = (const float*)d_in[5];
    const float* enc_g    = (const float*)d_in[6];
    const float* enc_beta = (const float*)d_in[7];
    const float* emb      = (const float*)d_in[8];
    const float* in_w     = (const float*)d_in[9];
    const float* in_b     = (const float*)d_in[10];
    const float* Wih      = (const float*)d_in[11];
    const float* Whh      = (const float*)d_in[12];
    const float* bih      = (const float*)d_in[13];
    const float* bhh      = (const float*)d_in[14];
    const float* ln_g     = (const float*)d_in[15];
    const float* ln_b     = (const float*)d_in[16];
    const float* W1       = (const float*)d_in[17];
    const float* b1       = (const float*)d_in[18];
    const float* W2       = (const float*)d_in[19];
    const float* b2       = (const float*)d_in[20];
    float* out = (float*)d_out;

    float* ws = (float*)d_ws;
    size_t off = 0;
    auto alloc = [&](size_t n) { float* p = ws + off; off += (n + 63) & ~(size_t)63; return p; };
    float* lgAll   = alloc((size_t)NT * NVOC * 64);   // aliased as fX pre-loop
    float* fX      = lgAll;
    float* featT   = alloc((size_t)NG * ND * 64);
    float* featB   = alloc((size_t)64 * NG * ND);
    float* gihxAll = alloc((size_t)NT * 64 * 2048);
    float* fmean   = alloc((size_t)ND * 64);
    float* qmean   = alloc((size_t)NE * 64);
    float* mq      = alloc((size_t)64 * 256);
    float* cSb     = alloc((size_t)64 * NH * NG);
    float* cT_     = alloc((size_t)64 * NU);
    float* qaT     = alloc((size_t)NE * 64);
    float* ghhT    = alloc((size_t)64 * 2048);
    float* Wc      = alloc((size_t)2048 * 32);
    float* zPm     = alloc((size_t)NT * 313 * 64);
    float* zInv    = alloc((size_t)NT * 64);
    unsigned short* WA   = (unsigned short*)alloc((size_t)2592 * 256);  // [2592][512] bf16: Wq rows 0..543, Whh rows 544..2591
    unsigned short* W1x  = (unsigned short*)alloc((size_t)256 * 256);   // [256][512] bf16
    unsigned short* abf  = (unsigned short*)alloc((size_t)64 * 256);    // [64][512] bf16, per-step a=LN(h)
    unsigned short* sbf  = (unsigned short*)alloc((size_t)960 * 256);   // [960][512] bf16, leaky(LN(h_t)) all t
    unsigned short* Wihx = (unsigned short*)alloc((size_t)2048 * 256);
    unsigned short* xbf  = (unsigned short*)alloc((size_t)960 * 256);
    unsigned short* W2bf = (unsigned short*)alloc((size_t)5008 * 128);
    unsigned short* h1bf = (unsigned short*)alloc((size_t)NT * 64 * 128);  // [960][256] bf16

    // weight prep
    kCvt<<<1088, 256, 0, stream>>>(in_w, NE, ND, 512, 544 * 512, WA);
    kCvt<<<4096, 256, 0, stream>>>(Whh, NU, 0, 512, 2048 * 512, WA + (size_t)544 * 512);
    kCvt<<<512, 256, 0, stream>>>(W1, NU, 0, 512, 256 * 512, W1x);
    kCvt<<<4096, 256, 0, stream>>>(Wih, NE, ND, 512, 2048 * 512, Wihx);
    kCvtW2<<<5008, 256, 0, stream>>>(W2, W2bf);
    kCvtWc<<<256, 256, 0, stream>>>(Wih, Wc);

    // precompute
    k_transpose_feat<<<563, 256, 0, stream>>>(features, fX);
    k_encoder2<<<NG, 256, 0, stream>>>(fX, enc_W, enc_b, enc_g, enc_beta, featT, featB);
    kInit<<<128, 256, 0, stream>>>(a0, c0, abf, cT_);
    kEmbed<<<NT, 256, 0, stream>>>(text, emb, xbf);
    k_featmean<<<8, 256, 0, stream>>>(featT, fmean);
    k_qmean<<<17, 256, 0, stream>>>(fmean, in_w, qmean);
    kM<<<8, 256, 0, stream>>>(qmean, in_w, mq);
    kCS<<<96, 256, 0, stream>>>(mq, featB, cSb);
    kGihxMF<<<1920, 256, 0, stream>>>(Wihx, xbf, bih, bhh, gihxAll);

    for (int t = 0; t < NT; ++t) {
        kAMF<<<162, 256, 0, stream>>>(WA, abf, in_b, qaT, ghhT);
        kStep<<<64, 256, 0, stream>>>(qaT, in_w, featB, cSb,
                                      gihxAll + (size_t)t * 64 * 2048, ghhT, Wc,
                                      ln_g, ln_b, cT_, abf, sbf, out, t);
    }

    kHeadMF<<<240, 256, 0, stream>>>(W1x, sbf, b1, h1bf);
    kLogitsMF<<<4695, 256, 0, stream>>>(W2bf, h1bf, b2, lgAll, zPm);
    kZinv<<<NT, 256, 0, stream>>>(zPm, zInv);
    kOut<<<NT * 79, 256, 0, stream>>>(lgAll, zInv, out);
}